// Round 7
// baseline (1900.795 us; speedup 1.0000x reference)
//
#include <hip/hip_runtime.h>
#include <math.h>

#define NB 759
#define NPT 220
#define KNN 10
#define XCCH 256
#define LDXC (XCCH * NPT)

typedef float f4 __attribute__((ext_vector_type(4)));
typedef float f16v __attribute__((ext_vector_type(16)));
typedef short bf8v __attribute__((ext_vector_type(8)));   // 8 bf16 in 4 VGPRs

// ---- bf16 split helpers (RNE). h+m+l reconstructs fp32 EXACTLY (24=3x8 bits).
__device__ inline unsigned short bfh(float x) {
  unsigned u = __float_as_uint(x);
  unsigned r = u + 0x7FFFu + ((u >> 16) & 1u);
  return (unsigned short)(r >> 16);
}
__device__ inline float bff(unsigned short h) {
  return __uint_as_float(((unsigned)h) << 16);
}
__device__ inline void bfsplit(float x, unsigned short& h, unsigned short& l) {
  h = bfh(x);
  l = bfh(x - bff(h));
}

// input (B,N,3) -> x0 (B,3,N)
__global__ __launch_bounds__(256) void k_transpose(const float* __restrict__ in, float* __restrict__ x0) {
  int i = blockIdx.x * 256 + threadIdx.x;
  if (i >= NB * 3 * NPT) return;
  int n = i % NPT; int t = i / NPT; int c = t % 3; int b = t / 3;
  x0[i] = in[(b * NPT + n) * 3 + c];
}

// W5 (512x256 fp32) -> Wh, Wl (bf16)
__global__ __launch_bounds__(256) void k_w5split(const float* __restrict__ W5,
    unsigned short* __restrict__ Wh, unsigned short* __restrict__ Wl) {
  int i = blockIdx.x * 256 + threadIdx.x;
  if (i >= 512 * 256) return;
  bfsplit(W5[i], Wh[i], Wl[i]);
}

__device__ inline void topk_insert(float d, int m, float* tv, int* ti) {
  if (d > tv[KNN - 1]) {      // strict >: ties keep earlier index (matches lax.top_k set)
    tv[KNN - 1] = d; ti[KNN - 1] = m;
    #pragma unroll
    for (int j = KNN - 1; j >= 1; --j) {
      if (tv[j] > tv[j - 1]) {
        float tf = tv[j - 1]; tv[j - 1] = tv[j]; tv[j] = tf;
        int tq = ti[j - 1]; ti[j - 1] = ti[j]; ti[j] = tq;
      } else break;
    }
  }
}

// kNN for C=3: cheap VALU version
__global__ __launch_bounds__(256) void k_knn3(const float* __restrict__ x, int ldb,
                                              int* __restrict__ idxout) {
  __shared__ __align__(16) float xl[NPT * 4];
  __shared__ float xx[NPT];
  int b = blockIdx.x;
  const float* xb = x + (size_t)b * ldb;
  for (int i = threadIdx.x; i < NPT; i += 256) {
    f4 v; v.x = xb[i]; v.y = xb[NPT + i]; v.z = xb[2 * NPT + i]; v.w = 0.f;
    *(f4*)&xl[i * 4] = v;
    xx[i] = v.x * v.x + v.y * v.y + v.z * v.z;
  }
  __syncthreads();
  int n = threadIdx.x;
  if (n >= NPT) return;
  f4 xn = *(const f4*)&xl[n * 4];
  float xxn = xx[n];
  float tv[KNN]; int ti[KNN];
  #pragma unroll
  for (int k = 0; k < KNN; ++k) { tv[k] = -1e30f; ti[k] = 0; }
  for (int m = 0; m < NPT; ++m) {
    f4 v = *(const f4*)&xl[m * 4];
    float dot = xn.x * v.x + xn.y * v.y + xn.z * v.z;
    topk_insert(2.f * dot - xxn - xx[m], m, tv, ti);
  }
  int* ib = idxout + ((size_t)b * NPT + n) * KNN;
  #pragma unroll
  for (int k = 0; k < KNN; ++k) ib[k] = ti[k];
}

// kNN via MFMA Gram matrix, 3-way bf16 split (6 products ~ fp32-exact).
template<int C>
__global__ __launch_bounds__(512) void k_knn_mfma(const float* __restrict__ x, int ldb,
                                                  int* __restrict__ idxout) {
  constexpr int KPG = C + 8;                 // row stride in bf16 (16B-aligned rows)
  constexpr int SW = (C / 16) - 1;           // swizzle mask
  __shared__ __align__(16) unsigned short XH[224 * KPG];
  __shared__ __align__(16) unsigned short XM[224 * KPG];
  __shared__ __align__(16) unsigned short XL[224 * KPG];
  __shared__ float xx[224];
  int b = blockIdx.x;
  const float* xb = x + (size_t)b * ldb;
  for (int i = threadIdx.x; i < C * 224; i += 512) {
    int c = i / 224, m = i - c * 224;
    float v = (m < NPT) ? xb[c * NPT + m] : 0.f;
    unsigned short h = bfh(v);
    float r1 = v - bff(h);
    unsigned short mm = bfh(r1);
    unsigned short l = bfh(r1 - bff(mm));
    int cs = c ^ ((m & SW) << 4);
    XH[m * KPG + cs] = h; XM[m * KPG + cs] = mm; XL[m * KPG + cs] = l;
  }
  for (int m = threadIdx.x; m < 224; m += 512) {
    float s = 0.f;
    if (m < NPT) {
      for (int c = 0; c < C; ++c) { float v = xb[c * NPT + m]; s += v * v; }
    } else s = 1e30f;
    xx[m] = s;
  }
  __syncthreads();
  int w = threadIdx.x >> 6;
  int lane = threadIdx.x & 63;
  int lc = lane & 31, hi = lane >> 5;
  float tv[KNN]; int ti[KNN];
  #pragma unroll
  for (int k = 0; k < KNN; ++k) { tv[k] = -1e30f; ti[k] = 0; }
  if (w < 7) {
    int n = w * 32 + lc;
    f16v acc[7];
    #pragma unroll
    for (int mt = 0; mt < 7; ++mt)
      #pragma unroll
      for (int i = 0; i < 16; ++i) acc[mt][i] = 0.f;
    #pragma unroll
    for (int ks = 0; ks < C / 16; ++ks) {
      int kb = ks * 16 + hi * 8;
      int nsw = kb ^ ((n & SW) << 4);
      bf8v bh = *(const bf8v*)&XH[n * KPG + nsw];
      bf8v bm = *(const bf8v*)&XM[n * KPG + nsw];
      bf8v bl = *(const bf8v*)&XL[n * KPG + nsw];
      #pragma unroll
      for (int mt = 0; mt < 7; ++mt) {
        int mr = mt * 32 + lc;
        int msw = kb ^ ((mr & SW) << 4);
        bf8v ah = *(const bf8v*)&XH[mr * KPG + msw];
        bf8v am = *(const bf8v*)&XM[mr * KPG + msw];
        bf8v al = *(const bf8v*)&XL[mr * KPG + msw];
        acc[mt] = __builtin_amdgcn_mfma_f32_32x32x16_bf16(ah, bh, acc[mt], 0, 0, 0);
        acc[mt] = __builtin_amdgcn_mfma_f32_32x32x16_bf16(am, bh, acc[mt], 0, 0, 0);
        acc[mt] = __builtin_amdgcn_mfma_f32_32x32x16_bf16(ah, bm, acc[mt], 0, 0, 0);
        acc[mt] = __builtin_amdgcn_mfma_f32_32x32x16_bf16(am, bm, acc[mt], 0, 0, 0);
        acc[mt] = __builtin_amdgcn_mfma_f32_32x32x16_bf16(al, bh, acc[mt], 0, 0, 0);
        acc[mt] = __builtin_amdgcn_mfma_f32_32x32x16_bf16(ah, bl, acc[mt], 0, 0, 0);
      }
    }
    float xxn = xx[n];
    #pragma unroll
    for (int mt = 0; mt < 7; ++mt)
      #pragma unroll
      for (int i = 0; i < 16; ++i) {
        int m = mt * 32 + (i & 3) + 8 * (i >> 2) + 4 * hi;
        float d = 2.f * acc[mt][i] - xx[m] - xxn;
        topk_insert(d, m, tv, ti);
      }
  }
  __syncthreads();
  float* LV = (float*)XH;
  int* LI = (int*)XM;
  if (w < 7) {
    int slot = (w * 64 + lane) * KNN;
    #pragma unroll
    for (int k = 0; k < KNN; ++k) { LV[slot + k] = tv[k]; LI[slot + k] = ti[k]; }
  }
  __syncthreads();
  if (w < 7 && hi == 0) {
    int n = w * 32 + lc;
    if (n < NPT) {
      int sa = (w * 64 + lane) * KNN, sb = sa + 32 * KNN;
      int a = 0, bq = 0;
      int* ob = idxout + ((size_t)b * NPT + n) * KNN;
      #pragma unroll
      for (int k = 0; k < KNN; ++k) {
        float va = LV[sa + a], vb = LV[sb + bq];
        int ia = LI[sa + a], ic = LI[sb + bq];
        bool ta = (va > vb) || (va == vb && ia < ic);
        ob[k] = ta ? ia : ic;
        if (ta) ++a; else ++bq;
      }
    }
  }
}

// Fused edge conv (R4 config: unroll 2, launch_bounds(256,2))
template<int CIN>
__global__ __launch_bounds__(256, 2) void k_conv_fused(const float* __restrict__ x, int ldb,
    const float* __restrict__ W, const int* __restrict__ idxb, float* __restrict__ xout) {
  constexpr int NPAD = 224;
  constexpr int DBS = 224;
  constexpr int REGION = 64 * DBS;
  __shared__ __align__(16) float smem[REGION + CIN * 64];
  __shared__ unsigned short idxl[NPT * KNN];
  float* xl = smem;
  float* db = smem;
  float* wl = smem + REGION;
  int b = blockIdx.x, og = blockIdx.y;
  const float* xb = x + (size_t)b * ldb;
  for (int i = threadIdx.x; i < CIN * NPAD; i += 256) {
    int c = i / NPAD, n = i - c * NPAD;
    xl[i] = (n < NPT) ? xb[c * NPT + n] : 0.f;
  }
  for (int i = threadIdx.x; i < 64 * CIN; i += 256) {
    int rl = i & 63, c = i >> 6;
    int o = og * 32 + (rl & 31);
    float wv = (rl < 32) ? W[o * 2 * CIN + c]
                         : (W[o * 2 * CIN + CIN + c] - W[o * 2 * CIN + c]);
    wl[c * 64 + rl] = wv;
  }
  for (int i = threadIdx.x; i < NPT * KNN; i += 256)
    idxl[i] = (unsigned short)idxb[(size_t)b * NPT * KNN + i];
  __syncthreads();
  int rq = threadIdx.x & 15, nq = threadIdx.x >> 4;
  int gv[4]; bool gok[4];
  #pragma unroll
  for (int j = 0; j < 4; ++j) { int g = nq + j * 16; gok[j] = g < 55; gv[j] = (g < 55 ? g : 54) * 4; }
  f4 acc[4][4];
  #pragma unroll
  for (int j = 0; j < 4; ++j)
    #pragma unroll
    for (int i2 = 0; i2 < 4; ++i2) acc[j][i2] = (f4){0.f, 0.f, 0.f, 0.f};
  #pragma unroll 2
  for (int c = 0; c < CIN; ++c) {
    f4 wv = *(const f4*)&wl[c * 64 + rq * 4];
    #pragma unroll
    for (int j = 0; j < 4; ++j) {
      f4 xv = *(const f4*)&xl[c * NPAD + gv[j]];
      acc[j][0] += wv.x * xv; acc[j][1] += wv.y * xv;
      acc[j][2] += wv.z * xv; acc[j][3] += wv.w * xv;
    }
  }
  __syncthreads();
  #pragma unroll
  for (int j = 0; j < 4; ++j) {
    if (gok[j]) {
      #pragma unroll
      for (int i2 = 0; i2 < 4; ++i2)
        *(f4*)&db[(rq * 4 + i2) * DBS + gv[j]] = acc[j][i2];
    }
  }
  __syncthreads();
  int o0 = og * 32;
  for (int i = threadIdx.x; i < 32 * NPT; i += 256) {
    int ol = i / NPT, n = i - ol * NPT;
    const float* drow = &db[ol * DBS];
    const unsigned short* ib = &idxl[n * KNN];
    float mx = -1e30f;
    #pragma unroll
    for (int k = 0; k < KNN; ++k) mx = fmaxf(mx, drow[ib[k]]);
    float v = mx + db[(32 + ol) * DBS + n];
    xout[((size_t)b * XCCH + o0 + ol) * NPT + n] = (v >= 0.f) ? v : 0.2f * v;
  }
}

// W5 GEMM via split-bf16 MFMA, R7 restructure: wave = col-tile (8 waves, 7
// active), row-tiles iterated with A (Wh/Wl) read from global (L2-resident,
// identical across waves -> broadcast). B-frag LDS reads: 224 -> 32 per wave.
// X tile stored [col][k64] with T2 XOR swizzle (granule ^= col&7), KP=64.
__global__ __launch_bounds__(512, 4) void k_w5_mfma(const float* __restrict__ xc,
    const unsigned short* __restrict__ Wh, const unsigned short* __restrict__ Wl,
    const float* __restrict__ g5, const float* __restrict__ b5, const float* __restrict__ m5,
    const float* __restrict__ v5, float* __restrict__ p) {
  __shared__ __align__(16) unsigned short XH[224 * 64];
  __shared__ __align__(16) unsigned short XL[224 * 64];
  __shared__ float red[128][8][2];
  __shared__ float ADq[128][2];
  int d = blockIdx.x;
  int b = (d & 7) * 95 + (d >> 5);     // XCD-swizzle: batch's 4 rg-blocks adjacent on one XCD
  int rg = (d >> 3) & 3;
  if (b >= NB) return;
  int lane = threadIdx.x & 63, w = threadIdx.x >> 6;
  int lc = lane & 31, hi = lane >> 5;

  // per-row bn coefficients once
  if (threadIdx.x < 128) {
    int row = rg * 128 + threadIdx.x;
    float a = g5[row] * rsqrtf(v5[row] + 1e-5f);
    ADq[threadIdx.x][0] = a;
    ADq[threadIdx.x][1] = b5[row] - m5[row] * a;
  }

  f16v acc[4];
  #pragma unroll
  for (int rt = 0; rt < 4; ++rt)
    #pragma unroll
    for (int i = 0; i < 16; ++i) acc[rt][i] = 0.f;

  for (int cb = 0; cb < 4; ++cb) {
    if (cb) __syncthreads();
    // stage+split 64k x 220 cols, packed dwords, T2 granule swizzle
    for (int i = threadIdx.x; i < 32 * NPT; i += 512) {
      int cp = i / NPT;          // channel pair 0..31
      int n = i - cp * NPT;      // col
      int c0 = cp * 2;
      const float* src = &xc[((size_t)b * XCCH + cb * 64 + c0) * NPT + n];
      float x0 = src[0];
      float x1 = src[NPT];
      unsigned short h0, l0, h1, l1;
      bfsplit(x0, h0, l0); bfsplit(x1, h1, l1);
      int dw = n * 32 + (((c0 >> 3) ^ (n & 7)) << 2) + ((c0 & 7) >> 1);
      ((unsigned*)XH)[dw] = (unsigned)h0 | ((unsigned)h1 << 16);
      ((unsigned*)XL)[dw] = (unsigned)l0 | ((unsigned)l1 << 16);
    }
    // zero-pad cols 220..223 (swizzle is a bijection within each row)
    for (int i = threadIdx.x; i < 128; i += 512) {
      int n = NPT + (i >> 5); int cd = i & 31;
      ((unsigned*)XH)[n * 32 + cd] = 0u;
      ((unsigned*)XL)[n * 32 + cd] = 0u;
    }
    __syncthreads();
    if (w < 7) {
      int col = w * 32 + lc;
      int swc = col & 7;
      const unsigned short* XHr = &XH[col * 64];
      const unsigned short* XLr = &XL[col * 64];
      #pragma unroll
      for (int ks = 0; ks < 4; ++ks) {
        int gr = (((ks * 2 + hi) ^ swc) << 3);
        bf8v bh = *(const bf8v*)&XHr[gr];
        bf8v bl = *(const bf8v*)&XLr[gr];
        int kg = cb * 64 + ks * 16 + hi * 8;
        const unsigned short* wp = Wh + (size_t)(rg * 128 + lc) * 256 + kg;
        const unsigned short* wq = Wl + (size_t)(rg * 128 + lc) * 256 + kg;
        #pragma unroll
        for (int rt = 0; rt < 4; ++rt) {
          bf8v ah = *(const bf8v*)(wp + rt * 32 * 256);
          bf8v al = *(const bf8v*)(wq + rt * 32 * 256);
          acc[rt] = __builtin_amdgcn_mfma_f32_32x32x16_bf16(ah, bh, acc[rt], 0, 0, 0);
          acc[rt] = __builtin_amdgcn_mfma_f32_32x32x16_bf16(al, bh, acc[rt], 0, 0, 0);
          acc[rt] = __builtin_amdgcn_mfma_f32_32x32x16_bf16(ah, bl, acc[rt], 0, 0, 0);
        }
      }
    }
  }
  // epilogue: bn+leaky, pool over this wave's 32 cols, then cross-wave reduce
  if (w < 7) {
    bool allv = (w < 6);
    #pragma unroll
    for (int rt = 0; rt < 4; ++rt) {
      #pragma unroll
      for (int i = 0; i < 16; ++i) {
        int rl = rt * 32 + (i & 3) + 8 * (i >> 2) + 4 * hi;
        float a = ADq[rl][0], dq = ADq[rl][1];
        float hv = a * acc[rt][i] + dq;
        float lv = (hv >= 0.f) ? hv : 0.2f * hv;
        bool valid = allv || (lc < 28);
        float mx = valid ? lv : -1e30f;
        float sm = valid ? lv : 0.f;
        #pragma unroll
        for (int m_ = 1; m_ <= 16; m_ <<= 1) {
          mx = fmaxf(mx, __shfl_xor(mx, m_));
          sm += __shfl_xor(sm, m_);
        }
        if (lc == 0) { red[rl][w][0] = mx; red[rl][w][1] = sm; }
      }
    }
  }
  __syncthreads();
  if (threadIdx.x < 128) {
    int rl = threadIdx.x;
    float mx = -1e30f, sm = 0.f;
    #pragma unroll
    for (int q = 0; q < 7; ++q) { mx = fmaxf(mx, red[rl][q][0]); sm += red[rl][q][1]; }
    int row = rg * 128 + rl;
    p[(size_t)b * 1024 + row] = mx;
    p[(size_t)b * 1024 + 512 + row] = sm * (1.f / NPT);
  }
}

// out[b][o] = in[b][:] . Wt[o][:]  (+ bn+leaky | + bias)
template<int ON, bool FUSE>
__global__ __launch_bounds__(256) void k_fc(const float* __restrict__ in, const float* __restrict__ Wt,
    const float* __restrict__ q0, const float* __restrict__ q1, const float* __restrict__ q2,
    const float* __restrict__ q3, float* __restrict__ out, int ostride) {
  __shared__ __align__(16) float il[32 * 68];
  __shared__ __align__(16) float wl[32 * 68];
  int b0 = blockIdx.x * 64, o0 = blockIdx.y * 64;
  int oq = threadIdx.x & 15, bq = threadIdx.x >> 4;
  f4 acc[4];
  #pragma unroll
  for (int i2 = 0; i2 < 4; ++i2) acc[i2] = (f4){0.f, 0.f, 0.f, 0.f};
  for (int cb = 0; cb < 32; ++cb) {
    if (cb) __syncthreads();
    for (int i = threadIdx.x; i < 2048; i += 256) {
      int c = i & 31, bb = i >> 5;
      il[c * 68 + bb] = (b0 + bb < NB) ? in[(b0 + bb) * 1024 + cb * 32 + c] : 0.f;
    }
    for (int i = threadIdx.x; i < 2048; i += 256) {
      int c = i & 31, ol = i >> 5;
      wl[c * 68 + ol] = (o0 + ol < ON) ? Wt[(o0 + ol) * 1024 + cb * 32 + c] : 0.f;
    }
    __syncthreads();
    #pragma unroll
    for (int c = 0; c < 32; ++c) {
      f4 wv = *(const f4*)&wl[c * 68 + oq * 4];
      f4 iv = *(const f4*)&il[c * 68 + bq * 4];
      acc[0] += wv.x * iv; acc[1] += wv.y * iv; acc[2] += wv.z * iv; acc[3] += wv.w * iv;
    }
  }
  #pragma unroll
  for (int i2 = 0; i2 < 4; ++i2) {
    int o = o0 + oq * 4 + i2;
    if (o >= ON) continue;
    float A = 1.f, Dv = 0.f;
    if (FUSE) { float a = q0[o] * rsqrtf(q3[o] + 1e-5f); A = a; Dv = q1[o] - q2[o] * a; }
    else { Dv = q0[o]; }
    #pragma unroll
    for (int jj = 0; jj < 4; ++jj) {
      int bb = b0 + bq * 4 + jj;
      if (bb < NB) {
        float v = acc[i2][jj];
        if (FUSE) { v = A * v + Dv; v = (v >= 0.f) ? v : 0.2f * v; }
        else { v = v + Dv; }
        out[(size_t)bb * ostride + o] = v;
      }
    }
  }
}

extern "C" void kernel_launch(void* const* d_in, const int* in_sizes, int n_in,
                              void* d_out, int out_size, void* d_ws, size_t ws_size,
                              hipStream_t stream) {
  const float* input = (const float*)d_in[0];
  const float* W1 = (const float*)d_in[1];
  const float* W2 = (const float*)d_in[2];
  const float* W3 = (const float*)d_in[3];
  const float* W4 = (const float*)d_in[4];
  const float* W5 = (const float*)d_in[5];
  const float* g5 = (const float*)d_in[6];
  const float* b5 = (const float*)d_in[7];
  const float* m5 = (const float*)d_in[8];
  const float* v5 = (const float*)d_in[9];
  const float* Wl1 = (const float*)d_in[10];
  const float* g6 = (const float*)d_in[11];
  const float* b6 = (const float*)d_in[12];
  const float* m6 = (const float*)d_in[13];
  const float* v6 = (const float*)d_in[14];
  const float* Wl2 = (const float*)d_in[15];
  const float* bl2 = (const float*)d_in[16];

  // workspace layout (floats): ~186.4 MB
  float* w = (float*)d_ws;
  float* x0 = w;                          //   500,940
  float* xc = x0 + 500940;                //  42,746,880
  float* p  = xc + 42746880;              //     777,216
  float* z  = p  + 777216;                //     777,216
  int* idxb = (int*)(z + 777216);         //   1,669,800 ints
  unsigned short* wh = (unsigned short*)(w + 46472052);  // 131,072 bf16 (16B-aligned)
  unsigned short* wlo = wh + 131072;

  k_transpose<<<1957, 256, 0, stream>>>(input, x0);
  k_w5split<<<512, 256, 0, stream>>>(W5, wh, wlo);

  k_knn3<<<759, 256, 0, stream>>>(x0, 3 * NPT, idxb);
  k_conv_fused<3><<<dim3(759, 1), 256, 0, stream>>>(x0, 3 * NPT, W1, idxb, xc);

  k_knn_mfma<32><<<759, 512, 0, stream>>>(xc, LDXC, idxb);
  k_conv_fused<32><<<dim3(759, 1), 256, 0, stream>>>(xc, LDXC, W2, idxb, xc + 32 * NPT);

  k_knn_mfma<32><<<759, 512, 0, stream>>>(xc + 32 * NPT, LDXC, idxb);
  k_conv_fused<32><<<dim3(759, 2), 256, 0, stream>>>(xc + 32 * NPT, LDXC, W3, idxb, xc + 64 * NPT);

  k_knn_mfma<64><<<759, 512, 0, stream>>>(xc + 64 * NPT, LDXC, idxb);
  k_conv_fused<64><<<dim3(759, 4), 256, 0, stream>>>(xc + 64 * NPT, LDXC, W4, idxb, xc + 128 * NPT);

  k_w5_mfma<<<3040, 512, 0, stream>>>(xc, wh, wlo, g5, b5, m5, v5, p);

  k_fc<1024, true><<<dim3(12, 16), 256, 0, stream>>>(p, Wl1, g6, b6, m6, v6, z, 1024);
  k_fc<380, false><<<dim3(12, 6), 256, 0, stream>>>(z, Wl2, bl2, bl2, bl2, bl2, (float*)d_out, 380);
}

// Round 8
// 1814.623 us; speedup vs baseline: 1.0475x; 1.0475x over previous
//
#include <hip/hip_runtime.h>
#include <math.h>

#define NB 759
#define NPT 220
#define KNN 10
#define XCCH 256
#define LDXC (XCCH * NPT)

typedef float f4 __attribute__((ext_vector_type(4)));
typedef float f16v __attribute__((ext_vector_type(16)));
typedef short bf8v __attribute__((ext_vector_type(8)));   // 8 bf16 in 4 VGPRs

// ---- bf16 split helpers (RNE). h+m+l reconstructs fp32 EXACTLY (24=3x8 bits).
__device__ inline unsigned short bfh(float x) {
  unsigned u = __float_as_uint(x);
  unsigned r = u + 0x7FFFu + ((u >> 16) & 1u);
  return (unsigned short)(r >> 16);
}
__device__ inline float bff(unsigned short h) {
  return __uint_as_float(((unsigned)h) << 16);
}
__device__ inline void bfsplit(float x, unsigned short& h, unsigned short& l) {
  h = bfh(x);
  l = bfh(x - bff(h));
}

// input (B,N,3) -> x0 (B,3,N)
__global__ __launch_bounds__(256) void k_transpose(const float* __restrict__ in, float* __restrict__ x0) {
  int i = blockIdx.x * 256 + threadIdx.x;
  if (i >= NB * 3 * NPT) return;
  int n = i % NPT; int t = i / NPT; int c = t % 3; int b = t / 3;
  x0[i] = in[(b * NPT + n) * 3 + c];
}

// W5 (512x256 fp32) -> Wh, Wl (bf16)
__global__ __launch_bounds__(256) void k_w5split(const float* __restrict__ W5,
    unsigned short* __restrict__ Wh, unsigned short* __restrict__ Wl) {
  int i = blockIdx.x * 256 + threadIdx.x;
  if (i >= 512 * 256) return;
  bfsplit(W5[i], Wh[i], Wl[i]);
}

__device__ inline void topk_insert(float d, int m, float* tv, int* ti) {
  if (d > tv[KNN - 1]) {      // strict >: ties keep earlier index (matches lax.top_k set)
    tv[KNN - 1] = d; ti[KNN - 1] = m;
    #pragma unroll
    for (int j = KNN - 1; j >= 1; --j) {
      if (tv[j] > tv[j - 1]) {
        float tf = tv[j - 1]; tv[j - 1] = tv[j]; tv[j] = tf;
        int tq = ti[j - 1]; ti[j - 1] = ti[j]; ti[j] = tq;
      } else break;
    }
  }
}

// kNN for C=3: cheap VALU version
__global__ __launch_bounds__(256) void k_knn3(const float* __restrict__ x, int ldb,
                                              int* __restrict__ idxout) {
  __shared__ __align__(16) float xl[NPT * 4];
  __shared__ float xx[NPT];
  int b = blockIdx.x;
  const float* xb = x + (size_t)b * ldb;
  for (int i = threadIdx.x; i < NPT; i += 256) {
    f4 v; v.x = xb[i]; v.y = xb[NPT + i]; v.z = xb[2 * NPT + i]; v.w = 0.f;
    *(f4*)&xl[i * 4] = v;
    xx[i] = v.x * v.x + v.y * v.y + v.z * v.z;
  }
  __syncthreads();
  int n = threadIdx.x;
  if (n >= NPT) return;
  f4 xn = *(const f4*)&xl[n * 4];
  float xxn = xx[n];
  float tv[KNN]; int ti[KNN];
  #pragma unroll
  for (int k = 0; k < KNN; ++k) { tv[k] = -1e30f; ti[k] = 0; }
  for (int m = 0; m < NPT; ++m) {
    f4 v = *(const f4*)&xl[m * 4];
    float dot = xn.x * v.x + xn.y * v.y + xn.z * v.z;
    topk_insert(2.f * dot - xxn - xx[m], m, tv, ti);
  }
  int* ib = idxout + ((size_t)b * NPT + n) * KNN;
  #pragma unroll
  for (int k = 0; k < KNN; ++k) ib[k] = ti[k];
}

// kNN via MFMA Gram matrix, 3-way bf16 split (6 products ~ fp32-exact).
template<int C>
__global__ __launch_bounds__(512) void k_knn_mfma(const float* __restrict__ x, int ldb,
                                                  int* __restrict__ idxout) {
  constexpr int KPG = C + 8;                 // row stride in bf16 (16B-aligned rows)
  constexpr int SW = (C / 16) - 1;           // swizzle mask
  __shared__ __align__(16) unsigned short XH[224 * KPG];
  __shared__ __align__(16) unsigned short XM[224 * KPG];
  __shared__ __align__(16) unsigned short XL[224 * KPG];
  __shared__ float xx[224];
  int b = blockIdx.x;
  const float* xb = x + (size_t)b * ldb;
  for (int i = threadIdx.x; i < C * 224; i += 512) {
    int c = i / 224, m = i - c * 224;
    float v = (m < NPT) ? xb[c * NPT + m] : 0.f;
    unsigned short h = bfh(v);
    float r1 = v - bff(h);
    unsigned short mm = bfh(r1);
    unsigned short l = bfh(r1 - bff(mm));
    int cs = c ^ ((m & SW) << 4);
    XH[m * KPG + cs] = h; XM[m * KPG + cs] = mm; XL[m * KPG + cs] = l;
  }
  for (int m = threadIdx.x; m < 224; m += 512) {
    float s = 0.f;
    if (m < NPT) {
      for (int c = 0; c < C; ++c) { float v = xb[c * NPT + m]; s += v * v; }
    } else s = 1e30f;
    xx[m] = s;
  }
  __syncthreads();
  int w = threadIdx.x >> 6;
  int lane = threadIdx.x & 63;
  int lc = lane & 31, hi = lane >> 5;
  float tv[KNN]; int ti[KNN];
  #pragma unroll
  for (int k = 0; k < KNN; ++k) { tv[k] = -1e30f; ti[k] = 0; }
  if (w < 7) {
    int n = w * 32 + lc;
    f16v acc[7];
    #pragma unroll
    for (int mt = 0; mt < 7; ++mt)
      #pragma unroll
      for (int i = 0; i < 16; ++i) acc[mt][i] = 0.f;
    #pragma unroll
    for (int ks = 0; ks < C / 16; ++ks) {
      int kb = ks * 16 + hi * 8;
      int nsw = kb ^ ((n & SW) << 4);
      bf8v bh = *(const bf8v*)&XH[n * KPG + nsw];
      bf8v bm = *(const bf8v*)&XM[n * KPG + nsw];
      bf8v bl = *(const bf8v*)&XL[n * KPG + nsw];
      #pragma unroll
      for (int mt = 0; mt < 7; ++mt) {
        int mr = mt * 32 + lc;
        int msw = kb ^ ((mr & SW) << 4);
        bf8v ah = *(const bf8v*)&XH[mr * KPG + msw];
        bf8v am = *(const bf8v*)&XM[mr * KPG + msw];
        bf8v al = *(const bf8v*)&XL[mr * KPG + msw];
        acc[mt] = __builtin_amdgcn_mfma_f32_32x32x16_bf16(ah, bh, acc[mt], 0, 0, 0);
        acc[mt] = __builtin_amdgcn_mfma_f32_32x32x16_bf16(am, bh, acc[mt], 0, 0, 0);
        acc[mt] = __builtin_amdgcn_mfma_f32_32x32x16_bf16(ah, bm, acc[mt], 0, 0, 0);
        acc[mt] = __builtin_amdgcn_mfma_f32_32x32x16_bf16(am, bm, acc[mt], 0, 0, 0);
        acc[mt] = __builtin_amdgcn_mfma_f32_32x32x16_bf16(al, bh, acc[mt], 0, 0, 0);
        acc[mt] = __builtin_amdgcn_mfma_f32_32x32x16_bf16(ah, bl, acc[mt], 0, 0, 0);
      }
    }
    float xxn = xx[n];
    #pragma unroll
    for (int mt = 0; mt < 7; ++mt)
      #pragma unroll
      for (int i = 0; i < 16; ++i) {
        int m = mt * 32 + (i & 3) + 8 * (i >> 2) + 4 * hi;
        float d = 2.f * acc[mt][i] - xx[m] - xxn;
        topk_insert(d, m, tv, ti);
      }
  }
  __syncthreads();
  float* LV = (float*)XH;
  int* LI = (int*)XM;
  if (w < 7) {
    int slot = (w * 64 + lane) * KNN;
    #pragma unroll
    for (int k = 0; k < KNN; ++k) { LV[slot + k] = tv[k]; LI[slot + k] = ti[k]; }
  }
  __syncthreads();
  if (w < 7 && hi == 0) {
    int n = w * 32 + lc;
    if (n < NPT) {
      int sa = (w * 64 + lane) * KNN, sb = sa + 32 * KNN;
      int a = 0, bq = 0;
      int* ob = idxout + ((size_t)b * NPT + n) * KNN;
      #pragma unroll
      for (int k = 0; k < KNN; ++k) {
        float va = LV[sa + a], vb = LV[sb + bq];
        int ia = LI[sa + a], ic = LI[sb + bq];
        bool ta = (va > vb) || (va == vb && ia < ic);
        ob[k] = ta ? ia : ic;
        if (ta) ++a; else ++bq;
      }
    }
  }
}

// Fused edge conv (R4 config: unroll 2, launch_bounds(256,2))
template<int CIN>
__global__ __launch_bounds__(256, 2) void k_conv_fused(const float* __restrict__ x, int ldb,
    const float* __restrict__ W, const int* __restrict__ idxb, float* __restrict__ xout) {
  constexpr int NPAD = 224;
  constexpr int DBS = 224;
  constexpr int REGION = 64 * DBS;
  __shared__ __align__(16) float smem[REGION + CIN * 64];
  __shared__ unsigned short idxl[NPT * KNN];
  float* xl = smem;
  float* db = smem;
  float* wl = smem + REGION;
  int b = blockIdx.x, og = blockIdx.y;
  const float* xb = x + (size_t)b * ldb;
  for (int i = threadIdx.x; i < CIN * NPAD; i += 256) {
    int c = i / NPAD, n = i - c * NPAD;
    xl[i] = (n < NPT) ? xb[c * NPT + n] : 0.f;
  }
  for (int i = threadIdx.x; i < 64 * CIN; i += 256) {
    int rl = i & 63, c = i >> 6;
    int o = og * 32 + (rl & 31);
    float wv = (rl < 32) ? W[o * 2 * CIN + c]
                         : (W[o * 2 * CIN + CIN + c] - W[o * 2 * CIN + c]);
    wl[c * 64 + rl] = wv;
  }
  for (int i = threadIdx.x; i < NPT * KNN; i += 256)
    idxl[i] = (unsigned short)idxb[(size_t)b * NPT * KNN + i];
  __syncthreads();
  int rq = threadIdx.x & 15, nq = threadIdx.x >> 4;
  int gv[4]; bool gok[4];
  #pragma unroll
  for (int j = 0; j < 4; ++j) { int g = nq + j * 16; gok[j] = g < 55; gv[j] = (g < 55 ? g : 54) * 4; }
  f4 acc[4][4];
  #pragma unroll
  for (int j = 0; j < 4; ++j)
    #pragma unroll
    for (int i2 = 0; i2 < 4; ++i2) acc[j][i2] = (f4){0.f, 0.f, 0.f, 0.f};
  #pragma unroll 2
  for (int c = 0; c < CIN; ++c) {
    f4 wv = *(const f4*)&wl[c * 64 + rq * 4];
    #pragma unroll
    for (int j = 0; j < 4; ++j) {
      f4 xv = *(const f4*)&xl[c * NPAD + gv[j]];
      acc[j][0] += wv.x * xv; acc[j][1] += wv.y * xv;
      acc[j][2] += wv.z * xv; acc[j][3] += wv.w * xv;
    }
  }
  __syncthreads();
  #pragma unroll
  for (int j = 0; j < 4; ++j) {
    if (gok[j]) {
      #pragma unroll
      for (int i2 = 0; i2 < 4; ++i2)
        *(f4*)&db[(rq * 4 + i2) * DBS + gv[j]] = acc[j][i2];
    }
  }
  __syncthreads();
  int o0 = og * 32;
  for (int i = threadIdx.x; i < 32 * NPT; i += 256) {
    int ol = i / NPT, n = i - ol * NPT;
    const float* drow = &db[ol * DBS];
    const unsigned short* ib = &idxl[n * KNN];
    float mx = -1e30f;
    #pragma unroll
    for (int k = 0; k < KNN; ++k) mx = fmaxf(mx, drow[ib[k]]);
    float v = mx + db[(32 + ol) * DBS + n];
    xout[((size_t)b * XCCH + o0 + ol) * NPT + n] = (v >= 0.f) ? v : 0.2f * v;
  }
}

// W5 GEMM via split-bf16 MFMA (R6 structure: wave=row-tile, A global x21
// amortized). R8: X-tile LDS layout [g=k/8][col 224][8 bf16] -> wave b128
// reads are 32x16B contiguous (ZERO bank conflicts); staging writes linear
// dwords (ZERO conflicts). MFMA order identical to R6 (bitwise-same output).
__global__ __launch_bounds__(256) void k_w5_mfma(const float* __restrict__ xc,
    const unsigned short* __restrict__ Wh, const unsigned short* __restrict__ Wl,
    const float* __restrict__ g5, const float* __restrict__ b5, const float* __restrict__ m5,
    const float* __restrict__ v5, float* __restrict__ p) {
  __shared__ __align__(16) unsigned short XH[8 * 224 * 8];   // [g][col][e]
  __shared__ __align__(16) unsigned short XL[8 * 224 * 8];
  int d = blockIdx.x;
  int b = (d & 7) * 95 + (d >> 5);     // XCD swizzle: batch's 4 rg-blocks on one XCD
  int rg = (d >> 3) & 3;
  if (b >= NB) return;
  int lane = threadIdx.x & 63, w = threadIdx.x >> 6;
  f16v acc[7];
  #pragma unroll
  for (int t = 0; t < 7; ++t)
    #pragma unroll
    for (int i = 0; i < 16; ++i) acc[t][i] = 0.f;

  int r = rg * 128 + w * 32 + (lane & 31);
  int khalf = (lane >> 5) * 8;
  unsigned* XHd = (unsigned*)XH;
  unsigned* XLd = (unsigned*)XL;

  for (int cb = 0; cb < 4; ++cb) {
    if (cb) __syncthreads();
    // stage+split: dword dwi = g*896 + n*4 + eh  (linear across threads ->
    // conflict-free LDS writes). k-pair c0 = g*8 + eh*2.
    for (int dwi = threadIdx.x; dwi < 7168; dwi += 256) {
      int g = dwi / 896;
      int rrem = dwi - g * 896;
      int n = rrem >> 2, eh = rrem & 3;
      int c0 = g * 8 + eh * 2;
      unsigned hpack = 0u, lpack = 0u;
      if (n < NPT) {
        const float* src = &xc[((size_t)b * XCCH + cb * 64 + c0) * NPT + n];
        float x0 = src[0];
        float x1 = src[NPT];
        unsigned short h0, l0, h1, l1;
        bfsplit(x0, h0, l0); bfsplit(x1, h1, l1);
        hpack = (unsigned)h0 | ((unsigned)h1 << 16);
        lpack = (unsigned)l0 | ((unsigned)l1 << 16);
      }
      XHd[dwi] = hpack;
      XLd[dwi] = lpack;
    }
    __syncthreads();
    #pragma unroll
    for (int ks = 0; ks < 4; ++ks) {
      int kg = cb * 64 + ks * 16 + khalf;
      int g = ks * 2 + (lane >> 5);          // k-granule within chunk
      bf8v ah = *(const bf8v*)&Wh[(size_t)r * 256 + kg];
      bf8v al = *(const bf8v*)&Wl[(size_t)r * 256 + kg];
      #pragma unroll
      for (int t = 0; t < 7; ++t) {
        int col = t * 32 + (lane & 31);
        bf8v bh = *(const bf8v*)&XH[g * 1792 + col * 8];
        bf8v bl = *(const bf8v*)&XL[g * 1792 + col * 8];
        acc[t] = __builtin_amdgcn_mfma_f32_32x32x16_bf16(ah, bh, acc[t], 0, 0, 0);
        acc[t] = __builtin_amdgcn_mfma_f32_32x32x16_bf16(al, bh, acc[t], 0, 0, 0);
        acc[t] = __builtin_amdgcn_mfma_f32_32x32x16_bf16(ah, bl, acc[t], 0, 0, 0);
      }
    }
  }
  int rbase = rg * 128 + w * 32 + 4 * (lane >> 5);
  int lc = lane & 31;
  #pragma unroll
  for (int i = 0; i < 16; ++i) {
    int row = rbase + (i & 3) + 8 * (i >> 2);
    float a = g5[row] * rsqrtf(v5[row] + 1e-5f);
    float dq = b5[row] - m5[row] * a;
    float mx = -1e30f, sm = 0.f;
    #pragma unroll
    for (int t = 0; t < 7; ++t) {
      bool valid = (t < 6) || (lc < 28);
      float hv = a * acc[t][i] + dq;
      float lv = (hv >= 0.f) ? hv : 0.2f * hv;
      if (valid) { mx = fmaxf(mx, lv); sm += lv; }
    }
    #pragma unroll
    for (int m_ = 1; m_ <= 16; m_ <<= 1) {
      mx = fmaxf(mx, __shfl_xor(mx, m_));
      sm += __shfl_xor(sm, m_);
    }
    if (lc == 0) {
      p[(size_t)b * 1024 + row] = mx;
      p[(size_t)b * 1024 + 512 + row] = sm * (1.f / NPT);
    }
  }
}

// out[b][o] = in[b][:] . Wt[o][:]  (+ bn+leaky | + bias)
template<int ON, bool FUSE>
__global__ __launch_bounds__(256) void k_fc(const float* __restrict__ in, const float* __restrict__ Wt,
    const float* __restrict__ q0, const float* __restrict__ q1, const float* __restrict__ q2,
    const float* __restrict__ q3, float* __restrict__ out, int ostride) {
  __shared__ __align__(16) float il[32 * 68];
  __shared__ __align__(16) float wl[32 * 68];
  int b0 = blockIdx.x * 64, o0 = blockIdx.y * 64;
  int oq = threadIdx.x & 15, bq = threadIdx.x >> 4;
  f4 acc[4];
  #pragma unroll
  for (int i2 = 0; i2 < 4; ++i2) acc[i2] = (f4){0.f, 0.f, 0.f, 0.f};
  for (int cb = 0; cb < 32; ++cb) {
    if (cb) __syncthreads();
    for (int i = threadIdx.x; i < 2048; i += 256) {
      int c = i & 31, bb = i >> 5;
      il[c * 68 + bb] = (b0 + bb < NB) ? in[(b0 + bb) * 1024 + cb * 32 + c] : 0.f;
    }
    for (int i = threadIdx.x; i < 2048; i += 256) {
      int c = i & 31, ol = i >> 5;
      wl[c * 68 + ol] = (o0 + ol < ON) ? Wt[(o0 + ol) * 1024 + cb * 32 + c] : 0.f;
    }
    __syncthreads();
    #pragma unroll
    for (int c = 0; c < 32; ++c) {
      f4 wv = *(const f4*)&wl[c * 68 + oq * 4];
      f4 iv = *(const f4*)&il[c * 68 + bq * 4];
      acc[0] += wv.x * iv; acc[1] += wv.y * iv; acc[2] += wv.z * iv; acc[3] += wv.w * iv;
    }
  }
  #pragma unroll
  for (int i2 = 0; i2 < 4; ++i2) {
    int o = o0 + oq * 4 + i2;
    if (o >= ON) continue;
    float A = 1.f, Dv = 0.f;
    if (FUSE) { float a = q0[o] * rsqrtf(q3[o] + 1e-5f); A = a; Dv = q1[o] - q2[o] * a; }
    else { Dv = q0[o]; }
    #pragma unroll
    for (int jj = 0; jj < 4; ++jj) {
      int bb = b0 + bq * 4 + jj;
      if (bb < NB) {
        float v = acc[i2][jj];
        if (FUSE) { v = A * v + Dv; v = (v >= 0.f) ? v : 0.2f * v; }
        else { v = v + Dv; }
        out[(size_t)bb * ostride + o] = v;
      }
    }
  }
}

extern "C" void kernel_launch(void* const* d_in, const int* in_sizes, int n_in,
                              void* d_out, int out_size, void* d_ws, size_t ws_size,
                              hipStream_t stream) {
  const float* input = (const float*)d_in[0];
  const float* W1 = (const float*)d_in[1];
  const float* W2 = (const float*)d_in[2];
  const float* W3 = (const float*)d_in[3];
  const float* W4 = (const float*)d_in[4];
  const float* W5 = (const float*)d_in[5];
  const float* g5 = (const float*)d_in[6];
  const float* b5 = (const float*)d_in[7];
  const float* m5 = (const float*)d_in[8];
  const float* v5 = (const float*)d_in[9];
  const float* Wl1 = (const float*)d_in[10];
  const float* g6 = (const float*)d_in[11];
  const float* b6 = (const float*)d_in[12];
  const float* m6 = (const float*)d_in[13];
  const float* v6 = (const float*)d_in[14];
  const float* Wl2 = (const float*)d_in[15];
  const float* bl2 = (const float*)d_in[16];

  // workspace layout (floats): ~186.4 MB
  float* w = (float*)d_ws;
  float* x0 = w;                          //   500,940
  float* xc = x0 + 500940;                //  42,746,880
  float* p  = xc + 42746880;              //     777,216
  float* z  = p  + 777216;                //     777,216
  int* idxb = (int*)(z + 777216);         //   1,669,800 ints
  unsigned short* wh = (unsigned short*)(w + 46472052);  // 131,072 bf16 (16B-aligned)
  unsigned short* wlo = wh + 131072;

  k_transpose<<<1957, 256, 0, stream>>>(input, x0);
  k_w5split<<<512, 256, 0, stream>>>(W5, wh, wlo);

  k_knn3<<<759, 256, 0, stream>>>(x0, 3 * NPT, idxb);
  k_conv_fused<3><<<dim3(759, 1), 256, 0, stream>>>(x0, 3 * NPT, W1, idxb, xc);

  k_knn_mfma<32><<<759, 512, 0, stream>>>(xc, LDXC, idxb);
  k_conv_fused<32><<<dim3(759, 1), 256, 0, stream>>>(xc, LDXC, W2, idxb, xc + 32 * NPT);

  k_knn_mfma<32><<<759, 512, 0, stream>>>(xc + 32 * NPT, LDXC, idxb);
  k_conv_fused<32><<<dim3(759, 2), 256, 0, stream>>>(xc + 32 * NPT, LDXC, W3, idxb, xc + 64 * NPT);

  k_knn_mfma<64><<<759, 512, 0, stream>>>(xc + 64 * NPT, LDXC, idxb);
  k_conv_fused<64><<<dim3(759, 4), 256, 0, stream>>>(xc + 64 * NPT, LDXC, W4, idxb, xc + 128 * NPT);

  k_w5_mfma<<<3040, 256, 0, stream>>>(xc, wh, wlo, g5, b5, m5, v5, p);

  k_fc<1024, true><<<dim3(12, 16), 256, 0, stream>>>(p, Wl1, g6, b6, m6, v6, z, 1024);
  k_fc<380, false><<<dim3(12, 6), 256, 0, stream>>>(z, Wl2, bl2, bl2, bl2, bl2, (float*)d_out, 380);
}

// Round 9
// 1773.716 us; speedup vs baseline: 1.0716x; 1.0231x over previous
//
#include <hip/hip_runtime.h>
#include <math.h>

#define NB 759
#define NPT 220
#define KNN 10
#define XCCH 256
#define LDXC (XCCH * NPT)

typedef float f4 __attribute__((ext_vector_type(4)));
typedef float f16v __attribute__((ext_vector_type(16)));
typedef short bf8v __attribute__((ext_vector_type(8)));   // 8 bf16 in 4 VGPRs

// ---- bf16 split helpers (RNE). h+m+l reconstructs fp32 EXACTLY (24=3x8 bits).
__device__ inline unsigned short bfh(float x) {
  unsigned u = __float_as_uint(x);
  unsigned r = u + 0x7FFFu + ((u >> 16) & 1u);
  return (unsigned short)(r >> 16);
}
__device__ inline float bff(unsigned short h) {
  return __uint_as_float(((unsigned)h) << 16);
}
__device__ inline void bfsplit(float x, unsigned short& h, unsigned short& l) {
  h = bfh(x);
  l = bfh(x - bff(h));
}

// input (B,N,3) -> x0 (B,3,N)
__global__ __launch_bounds__(256) void k_transpose(const float* __restrict__ in, float* __restrict__ x0) {
  int i = blockIdx.x * 256 + threadIdx.x;
  if (i >= NB * 3 * NPT) return;
  int n = i % NPT; int t = i / NPT; int c = t % 3; int b = t / 3;
  x0[i] = in[(b * NPT + n) * 3 + c];
}

// W5 (512x256 fp32) -> Wh, Wl (bf16)
__global__ __launch_bounds__(256) void k_w5split(const float* __restrict__ W5,
    unsigned short* __restrict__ Wh, unsigned short* __restrict__ Wl) {
  int i = blockIdx.x * 256 + threadIdx.x;
  if (i >= 512 * 256) return;
  bfsplit(W5[i], Wh[i], Wl[i]);
}

__device__ inline void topk_insert(float d, int m, float* tv, int* ti) {
  if (d > tv[KNN - 1]) {      // strict >: ties keep earlier index (matches lax.top_k set)
    tv[KNN - 1] = d; ti[KNN - 1] = m;
    #pragma unroll
    for (int j = KNN - 1; j >= 1; --j) {
      if (tv[j] > tv[j - 1]) {
        float tf = tv[j - 1]; tv[j - 1] = tv[j]; tv[j] = tf;
        int tq = ti[j - 1]; ti[j - 1] = ti[j]; ti[j] = tq;
      } else break;
    }
  }
}

// kNN for C=3: cheap VALU version
__global__ __launch_bounds__(256) void k_knn3(const float* __restrict__ x, int ldb,
                                              int* __restrict__ idxout) {
  __shared__ __align__(16) float xl[NPT * 4];
  __shared__ float xx[NPT];
  int b = blockIdx.x;
  const float* xb = x + (size_t)b * ldb;
  for (int i = threadIdx.x; i < NPT; i += 256) {
    f4 v; v.x = xb[i]; v.y = xb[NPT + i]; v.z = xb[2 * NPT + i]; v.w = 0.f;
    *(f4*)&xl[i * 4] = v;
    xx[i] = v.x * v.x + v.y * v.y + v.z * v.z;
  }
  __syncthreads();
  int n = threadIdx.x;
  if (n >= NPT) return;
  f4 xn = *(const f4*)&xl[n * 4];
  float xxn = xx[n];
  float tv[KNN]; int ti[KNN];
  #pragma unroll
  for (int k = 0; k < KNN; ++k) { tv[k] = -1e30f; ti[k] = 0; }
  for (int m = 0; m < NPT; ++m) {
    f4 v = *(const f4*)&xl[m * 4];
    float dot = xn.x * v.x + xn.y * v.y + xn.z * v.z;
    topk_insert(2.f * dot - xxn - xx[m], m, tv, ti);
  }
  int* ib = idxout + ((size_t)b * NPT + n) * KNN;
  #pragma unroll
  for (int k = 0; k < KNN; ++k) ib[k] = ti[k];
}

// kNN via MFMA Gram matrix, 3-way bf16 split (6 products ~ fp32-exact).
template<int C>
__global__ __launch_bounds__(512) void k_knn_mfma(const float* __restrict__ x, int ldb,
                                                  int* __restrict__ idxout) {
  constexpr int KPG = C + 8;                 // row stride in bf16 (16B-aligned rows)
  constexpr int SW = (C / 16) - 1;           // swizzle mask
  __shared__ __align__(16) unsigned short XH[224 * KPG];
  __shared__ __align__(16) unsigned short XM[224 * KPG];
  __shared__ __align__(16) unsigned short XL[224 * KPG];
  __shared__ float xx[224];
  int b = blockIdx.x;
  const float* xb = x + (size_t)b * ldb;
  for (int i = threadIdx.x; i < C * 224; i += 512) {
    int c = i / 224, m = i - c * 224;
    float v = (m < NPT) ? xb[c * NPT + m] : 0.f;
    unsigned short h = bfh(v);
    float r1 = v - bff(h);
    unsigned short mm = bfh(r1);
    unsigned short l = bfh(r1 - bff(mm));
    int cs = c ^ ((m & SW) << 4);
    XH[m * KPG + cs] = h; XM[m * KPG + cs] = mm; XL[m * KPG + cs] = l;
  }
  for (int m = threadIdx.x; m < 224; m += 512) {
    float s = 0.f;
    if (m < NPT) {
      for (int c = 0; c < C; ++c) { float v = xb[c * NPT + m]; s += v * v; }
    } else s = 1e30f;
    xx[m] = s;
  }
  __syncthreads();
  int w = threadIdx.x >> 6;
  int lane = threadIdx.x & 63;
  int lc = lane & 31, hi = lane >> 5;
  float tv[KNN]; int ti[KNN];
  #pragma unroll
  for (int k = 0; k < KNN; ++k) { tv[k] = -1e30f; ti[k] = 0; }
  if (w < 7) {
    int n = w * 32 + lc;
    f16v acc[7];
    #pragma unroll
    for (int mt = 0; mt < 7; ++mt)
      #pragma unroll
      for (int i = 0; i < 16; ++i) acc[mt][i] = 0.f;
    #pragma unroll
    for (int ks = 0; ks < C / 16; ++ks) {
      int kb = ks * 16 + hi * 8;
      int nsw = kb ^ ((n & SW) << 4);
      bf8v bh = *(const bf8v*)&XH[n * KPG + nsw];
      bf8v bm = *(const bf8v*)&XM[n * KPG + nsw];
      bf8v bl = *(const bf8v*)&XL[n * KPG + nsw];
      #pragma unroll
      for (int mt = 0; mt < 7; ++mt) {
        int mr = mt * 32 + lc;
        int msw = kb ^ ((mr & SW) << 4);
        bf8v ah = *(const bf8v*)&XH[mr * KPG + msw];
        bf8v am = *(const bf8v*)&XM[mr * KPG + msw];
        bf8v al = *(const bf8v*)&XL[mr * KPG + msw];
        acc[mt] = __builtin_amdgcn_mfma_f32_32x32x16_bf16(ah, bh, acc[mt], 0, 0, 0);
        acc[mt] = __builtin_amdgcn_mfma_f32_32x32x16_bf16(am, bh, acc[mt], 0, 0, 0);
        acc[mt] = __builtin_amdgcn_mfma_f32_32x32x16_bf16(ah, bm, acc[mt], 0, 0, 0);
        acc[mt] = __builtin_amdgcn_mfma_f32_32x32x16_bf16(am, bm, acc[mt], 0, 0, 0);
        acc[mt] = __builtin_amdgcn_mfma_f32_32x32x16_bf16(al, bh, acc[mt], 0, 0, 0);
        acc[mt] = __builtin_amdgcn_mfma_f32_32x32x16_bf16(ah, bl, acc[mt], 0, 0, 0);
      }
    }
    float xxn = xx[n];
    #pragma unroll
    for (int mt = 0; mt < 7; ++mt)
      #pragma unroll
      for (int i = 0; i < 16; ++i) {
        int m = mt * 32 + (i & 3) + 8 * (i >> 2) + 4 * hi;
        float d = 2.f * acc[mt][i] - xx[m] - xxn;
        topk_insert(d, m, tv, ti);
      }
  }
  __syncthreads();
  float* LV = (float*)XH;
  int* LI = (int*)XM;
  if (w < 7) {
    int slot = (w * 64 + lane) * KNN;
    #pragma unroll
    for (int k = 0; k < KNN; ++k) { LV[slot + k] = tv[k]; LI[slot + k] = ti[k]; }
  }
  __syncthreads();
  if (w < 7 && hi == 0) {
    int n = w * 32 + lc;
    if (n < NPT) {
      int sa = (w * 64 + lane) * KNN, sb = sa + 32 * KNN;
      int a = 0, bq = 0;
      int* ob = idxout + ((size_t)b * NPT + n) * KNN;
      #pragma unroll
      for (int k = 0; k < KNN; ++k) {
        float va = LV[sa + a], vb = LV[sb + bq];
        int ia = LI[sa + a], ic = LI[sb + bq];
        bool ta = (va > vb) || (va == vb && ia < ic);
        ob[k] = ta ? ia : ic;
        if (ta) ++a; else ++bq;
      }
    }
  }
}

// Fused edge conv (R4 config: unroll 2, launch_bounds(256,2))
template<int CIN>
__global__ __launch_bounds__(256, 2) void k_conv_fused(const float* __restrict__ x, int ldb,
    const float* __restrict__ W, const int* __restrict__ idxb, float* __restrict__ xout) {
  constexpr int NPAD = 224;
  constexpr int DBS = 224;
  constexpr int REGION = 64 * DBS;
  __shared__ __align__(16) float smem[REGION + CIN * 64];
  __shared__ unsigned short idxl[NPT * KNN];
  float* xl = smem;
  float* db = smem;
  float* wl = smem + REGION;
  int b = blockIdx.x, og = blockIdx.y;
  const float* xb = x + (size_t)b * ldb;
  for (int i = threadIdx.x; i < CIN * NPAD; i += 256) {
    int c = i / NPAD, n = i - c * NPAD;
    xl[i] = (n < NPT) ? xb[c * NPT + n] : 0.f;
  }
  for (int i = threadIdx.x; i < 64 * CIN; i += 256) {
    int rl = i & 63, c = i >> 6;
    int o = og * 32 + (rl & 31);
    float wv = (rl < 32) ? W[o * 2 * CIN + c]
                         : (W[o * 2 * CIN + CIN + c] - W[o * 2 * CIN + c]);
    wl[c * 64 + rl] = wv;
  }
  for (int i = threadIdx.x; i < NPT * KNN; i += 256)
    idxl[i] = (unsigned short)idxb[(size_t)b * NPT * KNN + i];
  __syncthreads();
  int rq = threadIdx.x & 15, nq = threadIdx.x >> 4;
  int gv[4]; bool gok[4];
  #pragma unroll
  for (int j = 0; j < 4; ++j) { int g = nq + j * 16; gok[j] = g < 55; gv[j] = (g < 55 ? g : 54) * 4; }
  f4 acc[4][4];
  #pragma unroll
  for (int j = 0; j < 4; ++j)
    #pragma unroll
    for (int i2 = 0; i2 < 4; ++i2) acc[j][i2] = (f4){0.f, 0.f, 0.f, 0.f};
  #pragma unroll 2
  for (int c = 0; c < CIN; ++c) {
    f4 wv = *(const f4*)&wl[c * 64 + rq * 4];
    #pragma unroll
    for (int j = 0; j < 4; ++j) {
      f4 xv = *(const f4*)&xl[c * NPAD + gv[j]];
      acc[j][0] += wv.x * xv; acc[j][1] += wv.y * xv;
      acc[j][2] += wv.z * xv; acc[j][3] += wv.w * xv;
    }
  }
  __syncthreads();
  #pragma unroll
  for (int j = 0; j < 4; ++j) {
    if (gok[j]) {
      #pragma unroll
      for (int i2 = 0; i2 < 4; ++i2)
        *(f4*)&db[(rq * 4 + i2) * DBS + gv[j]] = acc[j][i2];
    }
  }
  __syncthreads();
  int o0 = og * 32;
  for (int i = threadIdx.x; i < 32 * NPT; i += 256) {
    int ol = i / NPT, n = i - ol * NPT;
    const float* drow = &db[ol * DBS];
    const unsigned short* ib = &idxl[n * KNN];
    float mx = -1e30f;
    #pragma unroll
    for (int k = 0; k < KNN; ++k) mx = fmaxf(mx, drow[ib[k]]);
    float v = mx + db[(32 + ol) * DBS + n];
    xout[((size_t)b * XCCH + o0 + ol) * NPT + n] = (v >= 0.f) ? v : 0.2f * v;
  }
}

// W5 GEMM via split-bf16 MFMA (R6 structure: wave=row-tile, A global x21
// amortized). R9: 32-k chunks -> LDS 28KB -> 4 blocks/CU (16 waves, 2x latency
// hiding vs R8); staging reads restored to R6's 256B-coalesced mapping; reads
// keep R8's conflict-free [g][col][8] layout. Global k16 MFMA order identical
// to R8 -> bitwise-same output.
__global__ __launch_bounds__(256) void k_w5_mfma(const float* __restrict__ xc,
    const unsigned short* __restrict__ Wh, const unsigned short* __restrict__ Wl,
    const float* __restrict__ g5, const float* __restrict__ b5, const float* __restrict__ m5,
    const float* __restrict__ v5, float* __restrict__ p) {
  __shared__ __align__(16) unsigned short XH[4 * 224 * 8];   // [g][col][e] 14KB
  __shared__ __align__(16) unsigned short XL[4 * 224 * 8];
  int d = blockIdx.x;
  int b = (d & 7) * 95 + (d >> 5);     // XCD swizzle: batch's 4 rg-blocks on one XCD
  int rg = (d >> 3) & 3;
  if (b >= NB) return;
  int lane = threadIdx.x & 63, w = threadIdx.x >> 6;
  f16v acc[7];
  #pragma unroll
  for (int t = 0; t < 7; ++t)
    #pragma unroll
    for (int i = 0; i < 16; ++i) acc[t][i] = 0.f;

  int r = rg * 128 + w * 32 + (lane & 31);
  int khalf = (lane >> 5) * 8;
  unsigned* XHd = (unsigned*)XH;
  unsigned* XLd = (unsigned*)XL;

  for (int cb = 0; cb < 8; ++cb) {
    if (cb) __syncthreads();
    // stage+split 32k x 220n: coalesced global reads (consecutive n per lane),
    // dword write dw = g*896 + n*4 + eh  (g = cp>>2, eh = cp&3)
    for (int i = threadIdx.x; i < 16 * NPT; i += 256) {
      int cp = i / NPT;
      int n = i - cp * NPT;
      int c0 = cb * 32 + cp * 2;
      const float* src = &xc[((size_t)b * XCCH + c0) * NPT + n];
      float x0 = src[0];
      float x1 = src[NPT];
      unsigned short h0, l0, h1, l1;
      bfsplit(x0, h0, l0); bfsplit(x1, h1, l1);
      int dw = (cp >> 2) * 896 + n * 4 + (cp & 3);
      XHd[dw] = (unsigned)h0 | ((unsigned)h1 << 16);
      XLd[dw] = (unsigned)l0 | ((unsigned)l1 << 16);
    }
    // zero-pad cols 220..223 (4 g x 4 n x 4 eh)
    for (int i = threadIdx.x; i < 64; i += 256) {
      int g = i >> 4, n = NPT + ((i >> 2) & 3), eh = i & 3;
      int dw = g * 896 + n * 4 + eh;
      XHd[dw] = 0u;
      XLd[dw] = 0u;
    }
    __syncthreads();
    #pragma unroll
    for (int ks = 0; ks < 2; ++ks) {
      int kg = cb * 32 + ks * 16 + khalf;
      int g = ks * 2 + (lane >> 5);          // k-granule within chunk
      bf8v ah = *(const bf8v*)&Wh[(size_t)r * 256 + kg];
      bf8v al = *(const bf8v*)&Wl[(size_t)r * 256 + kg];
      #pragma unroll
      for (int t = 0; t < 7; ++t) {
        int col = t * 32 + (lane & 31);
        bf8v bh = *(const bf8v*)&XH[g * 1792 + col * 8];
        bf8v bl = *(const bf8v*)&XL[g * 1792 + col * 8];
        acc[t] = __builtin_amdgcn_mfma_f32_32x32x16_bf16(ah, bh, acc[t], 0, 0, 0);
        acc[t] = __builtin_amdgcn_mfma_f32_32x32x16_bf16(al, bh, acc[t], 0, 0, 0);
        acc[t] = __builtin_amdgcn_mfma_f32_32x32x16_bf16(ah, bl, acc[t], 0, 0, 0);
      }
    }
  }
  int rbase = rg * 128 + w * 32 + 4 * (lane >> 5);
  int lc = lane & 31;
  #pragma unroll
  for (int i = 0; i < 16; ++i) {
    int row = rbase + (i & 3) + 8 * (i >> 2);
    float a = g5[row] * rsqrtf(v5[row] + 1e-5f);
    float dq = b5[row] - m5[row] * a;
    float mx = -1e30f, sm = 0.f;
    #pragma unroll
    for (int t = 0; t < 7; ++t) {
      bool valid = (t < 6) || (lc < 28);
      float hv = a * acc[t][i] + dq;
      float lv = (hv >= 0.f) ? hv : 0.2f * hv;
      if (valid) { mx = fmaxf(mx, lv); sm += lv; }
    }
    #pragma unroll
    for (int m_ = 1; m_ <= 16; m_ <<= 1) {
      mx = fmaxf(mx, __shfl_xor(mx, m_));
      sm += __shfl_xor(sm, m_);
    }
    if (lc == 0) {
      p[(size_t)b * 1024 + row] = mx;
      p[(size_t)b * 1024 + 512 + row] = sm * (1.f / NPT);
    }
  }
}

// out[b][o] = in[b][:] . Wt[o][:]  (+ bn+leaky | + bias)
template<int ON, bool FUSE>
__global__ __launch_bounds__(256) void k_fc(const float* __restrict__ in, const float* __restrict__ Wt,
    const float* __restrict__ q0, const float* __restrict__ q1, const float* __restrict__ q2,
    const float* __restrict__ q3, float* __restrict__ out, int ostride) {
  __shared__ __align__(16) float il[32 * 68];
  __shared__ __align__(16) float wl[32 * 68];
  int b0 = blockIdx.x * 64, o0 = blockIdx.y * 64;
  int oq = threadIdx.x & 15, bq = threadIdx.x >> 4;
  f4 acc[4];
  #pragma unroll
  for (int i2 = 0; i2 < 4; ++i2) acc[i2] = (f4){0.f, 0.f, 0.f, 0.f};
  for (int cb = 0; cb < 32; ++cb) {
    if (cb) __syncthreads();
    for (int i = threadIdx.x; i < 2048; i += 256) {
      int c = i & 31, bb = i >> 5;
      il[c * 68 + bb] = (b0 + bb < NB) ? in[(b0 + bb) * 1024 + cb * 32 + c] : 0.f;
    }
    for (int i = threadIdx.x; i < 2048; i += 256) {
      int c = i & 31, ol = i >> 5;
      wl[c * 68 + ol] = (o0 + ol < ON) ? Wt[(o0 + ol) * 1024 + cb * 32 + c] : 0.f;
    }
    __syncthreads();
    #pragma unroll
    for (int c = 0; c < 32; ++c) {
      f4 wv = *(const f4*)&wl[c * 68 + oq * 4];
      f4 iv = *(const f4*)&il[c * 68 + bq * 4];
      acc[0] += wv.x * iv; acc[1] += wv.y * iv; acc[2] += wv.z * iv; acc[3] += wv.w * iv;
    }
  }
  #pragma unroll
  for (int i2 = 0; i2 < 4; ++i2) {
    int o = o0 + oq * 4 + i2;
    if (o >= ON) continue;
    float A = 1.f, Dv = 0.f;
    if (FUSE) { float a = q0[o] * rsqrtf(q3[o] + 1e-5f); A = a; Dv = q1[o] - q2[o] * a; }
    else { Dv = q0[o]; }
    #pragma unroll
    for (int jj = 0; jj < 4; ++jj) {
      int bb = b0 + bq * 4 + jj;
      if (bb < NB) {
        float v = acc[i2][jj];
        if (FUSE) { v = A * v + Dv; v = (v >= 0.f) ? v : 0.2f * v; }
        else { v = v + Dv; }
        out[(size_t)bb * ostride + o] = v;
      }
    }
  }
}

extern "C" void kernel_launch(void* const* d_in, const int* in_sizes, int n_in,
                              void* d_out, int out_size, void* d_ws, size_t ws_size,
                              hipStream_t stream) {
  const float* input = (const float*)d_in[0];
  const float* W1 = (const float*)d_in[1];
  const float* W2 = (const float*)d_in[2];
  const float* W3 = (const float*)d_in[3];
  const float* W4 = (const float*)d_in[4];
  const float* W5 = (const float*)d_in[5];
  const float* g5 = (const float*)d_in[6];
  const float* b5 = (const float*)d_in[7];
  const float* m5 = (const float*)d_in[8];
  const float* v5 = (const float*)d_in[9];
  const float* Wl1 = (const float*)d_in[10];
  const float* g6 = (const float*)d_in[11];
  const float* b6 = (const float*)d_in[12];
  const float* m6 = (const float*)d_in[13];
  const float* v6 = (const float*)d_in[14];
  const float* Wl2 = (const float*)d_in[15];
  const float* bl2 = (const float*)d_in[16];

  // workspace layout (floats): ~186.4 MB
  float* w = (float*)d_ws;
  float* x0 = w;                          //   500,940
  float* xc = x0 + 500940;                //  42,746,880
  float* p  = xc + 42746880;              //     777,216
  float* z  = p  + 777216;                //     777,216
  int* idxb = (int*)(z + 777216);         //   1,669,800 ints
  unsigned short* wh = (unsigned short*)(w + 46472052);  // 131,072 bf16 (16B-aligned)
  unsigned short* wlo = wh + 131072;

  k_transpose<<<1957, 256, 0, stream>>>(input, x0);
  k_w5split<<<512, 256, 0, stream>>>(W5, wh, wlo);

  k_knn3<<<759, 256, 0, stream>>>(x0, 3 * NPT, idxb);
  k_conv_fused<3><<<dim3(759, 1), 256, 0, stream>>>(x0, 3 * NPT, W1, idxb, xc);

  k_knn_mfma<32><<<759, 512, 0, stream>>>(xc, LDXC, idxb);
  k_conv_fused<32><<<dim3(759, 1), 256, 0, stream>>>(xc, LDXC, W2, idxb, xc + 32 * NPT);

  k_knn_mfma<32><<<759, 512, 0, stream>>>(xc + 32 * NPT, LDXC, idxb);
  k_conv_fused<32><<<dim3(759, 2), 256, 0, stream>>>(xc + 32 * NPT, LDXC, W3, idxb, xc + 64 * NPT);

  k_knn_mfma<64><<<759, 512, 0, stream>>>(xc + 64 * NPT, LDXC, idxb);
  k_conv_fused<64><<<dim3(759, 4), 256, 0, stream>>>(xc + 64 * NPT, LDXC, W4, idxb, xc + 128 * NPT);

  k_w5_mfma<<<3040, 256, 0, stream>>>(xc, wh, wlo, g5, b5, m5, v5, p);

  k_fc<1024, true><<<dim3(12, 16), 256, 0, stream>>>(p, Wl1, g6, b6, m6, v6, z, 1024);
  k_fc<380, false><<<dim3(12, 6), 256, 0, stream>>>(z, Wl2, bl2, bl2, bl2, bl2, (float*)d_out, 380);
}

// Round 10
// 1720.780 us; speedup vs baseline: 1.1046x; 1.0308x over previous
//
#include <hip/hip_runtime.h>
#include <math.h>

#define NB 759
#define NPT 220
#define KNN 10
#define XCCH 256
#define LDXC (XCCH * NPT)

typedef float f4 __attribute__((ext_vector_type(4)));
typedef float f16v __attribute__((ext_vector_type(16)));
typedef short bf8v __attribute__((ext_vector_type(8)));   // 8 bf16 in 4 VGPRs
typedef unsigned u4v __attribute__((ext_vector_type(4))); // 16B copy unit

// ---- bf16 split helpers (RNE). h+m+l reconstructs fp32 ~exactly (24=3x8 bits).
__device__ inline unsigned short bfh(float x) {
  unsigned u = __float_as_uint(x);
  unsigned r = u + 0x7FFFu + ((u >> 16) & 1u);
  return (unsigned short)(r >> 16);
}
__device__ inline float bff(unsigned short h) {
  return __uint_as_float(((unsigned)h) << 16);
}
__device__ inline void bfsplit(float x, unsigned short& h, unsigned short& l) {
  h = bfh(x);
  l = bfh(x - bff(h));
}

// input (B,N,3) -> x0 (B,3,N)
__global__ __launch_bounds__(256) void k_transpose(const float* __restrict__ in, float* __restrict__ x0) {
  int i = blockIdx.x * 256 + threadIdx.x;
  if (i >= NB * 3 * NPT) return;
  int n = i % NPT; int t = i / NPT; int c = t % 3; int b = t / 3;
  x0[i] = in[(b * NPT + n) * 3 + c];
}

// W5 (512x256 fp32) -> Wh, Wl (bf16)
__global__ __launch_bounds__(256) void k_w5split(const float* __restrict__ W5,
    unsigned short* __restrict__ Wh, unsigned short* __restrict__ Wl) {
  int i = blockIdx.x * 256 + threadIdx.x;
  if (i >= 512 * 256) return;
  bfsplit(W5[i], Wh[i], Wl[i]);
}

__device__ inline void topk_insert(float d, int m, float* tv, int* ti) {
  if (d > tv[KNN - 1]) {      // strict >: ties keep earlier index (matches lax.top_k set)
    tv[KNN - 1] = d; ti[KNN - 1] = m;
    #pragma unroll
    for (int j = KNN - 1; j >= 1; --j) {
      if (tv[j] > tv[j - 1]) {
        float tf = tv[j - 1]; tv[j - 1] = tv[j]; tv[j] = tf;
        int tq = ti[j - 1]; ti[j - 1] = ti[j]; ti[j] = tq;
      } else break;
    }
  }
}

// kNN for C=3: cheap VALU version
__global__ __launch_bounds__(256) void k_knn3(const float* __restrict__ x, int ldb,
                                              int* __restrict__ idxout) {
  __shared__ __align__(16) float xl[NPT * 4];
  __shared__ float xx[NPT];
  int b = blockIdx.x;
  const float* xb = x + (size_t)b * ldb;
  for (int i = threadIdx.x; i < NPT; i += 256) {
    f4 v; v.x = xb[i]; v.y = xb[NPT + i]; v.z = xb[2 * NPT + i]; v.w = 0.f;
    *(f4*)&xl[i * 4] = v;
    xx[i] = v.x * v.x + v.y * v.y + v.z * v.z;
  }
  __syncthreads();
  int n = threadIdx.x;
  if (n >= NPT) return;
  f4 xn = *(const f4*)&xl[n * 4];
  float xxn = xx[n];
  float tv[KNN]; int ti[KNN];
  #pragma unroll
  for (int k = 0; k < KNN; ++k) { tv[k] = -1e30f; ti[k] = 0; }
  for (int m = 0; m < NPT; ++m) {
    f4 v = *(const f4*)&xl[m * 4];
    float dot = xn.x * v.x + xn.y * v.y + xn.z * v.z;
    topk_insert(2.f * dot - xxn - xx[m], m, tv, ti);
  }
  int* ib = idxout + ((size_t)b * NPT + n) * KNN;
  #pragma unroll
  for (int k = 0; k < KNN; ++k) ib[k] = ti[k];
}

// kNN via MFMA Gram matrix, 3-way bf16 split (6 products ~ fp32-exact).
template<int C>
__global__ __launch_bounds__(512) void k_knn_mfma(const float* __restrict__ x, int ldb,
                                                  int* __restrict__ idxout) {
  constexpr int KPG = C + 8;
  constexpr int SW = (C / 16) - 1;
  __shared__ __align__(16) unsigned short XH[224 * KPG];
  __shared__ __align__(16) unsigned short XM[224 * KPG];
  __shared__ __align__(16) unsigned short XL[224 * KPG];
  __shared__ float xx[224];
  int b = blockIdx.x;
  const float* xb = x + (size_t)b * ldb;
  for (int i = threadIdx.x; i < C * 224; i += 512) {
    int c = i / 224, m = i - c * 224;
    float v = (m < NPT) ? xb[c * NPT + m] : 0.f;
    unsigned short h = bfh(v);
    float r1 = v - bff(h);
    unsigned short mm = bfh(r1);
    unsigned short l = bfh(r1 - bff(mm));
    int cs = c ^ ((m & SW) << 4);
    XH[m * KPG + cs] = h; XM[m * KPG + cs] = mm; XL[m * KPG + cs] = l;
  }
  for (int m = threadIdx.x; m < 224; m += 512) {
    float s = 0.f;
    if (m < NPT) {
      for (int c = 0; c < C; ++c) { float v = xb[c * NPT + m]; s += v * v; }
    } else s = 1e30f;
    xx[m] = s;
  }
  __syncthreads();
  int w = threadIdx.x >> 6;
  int lane = threadIdx.x & 63;
  int lc = lane & 31, hi = lane >> 5;
  float tv[KNN]; int ti[KNN];
  #pragma unroll
  for (int k = 0; k < KNN; ++k) { tv[k] = -1e30f; ti[k] = 0; }
  if (w < 7) {
    int n = w * 32 + lc;
    f16v acc[7];
    #pragma unroll
    for (int mt = 0; mt < 7; ++mt)
      #pragma unroll
      for (int i = 0; i < 16; ++i) acc[mt][i] = 0.f;
    #pragma unroll
    for (int ks = 0; ks < C / 16; ++ks) {
      int kb = ks * 16 + hi * 8;
      int nsw = kb ^ ((n & SW) << 4);
      bf8v bh = *(const bf8v*)&XH[n * KPG + nsw];
      bf8v bm = *(const bf8v*)&XM[n * KPG + nsw];
      bf8v bl = *(const bf8v*)&XL[n * KPG + nsw];
      #pragma unroll
      for (int mt = 0; mt < 7; ++mt) {
        int mr = mt * 32 + lc;
        int msw = kb ^ ((mr & SW) << 4);
        bf8v ah = *(const bf8v*)&XH[mr * KPG + msw];
        bf8v am = *(const bf8v*)&XM[mr * KPG + msw];
        bf8v al = *(const bf8v*)&XL[mr * KPG + msw];
        acc[mt] = __builtin_amdgcn_mfma_f32_32x32x16_bf16(ah, bh, acc[mt], 0, 0, 0);
        acc[mt] = __builtin_amdgcn_mfma_f32_32x32x16_bf16(am, bh, acc[mt], 0, 0, 0);
        acc[mt] = __builtin_amdgcn_mfma_f32_32x32x16_bf16(ah, bm, acc[mt], 0, 0, 0);
        acc[mt] = __builtin_amdgcn_mfma_f32_32x32x16_bf16(am, bm, acc[mt], 0, 0, 0);
        acc[mt] = __builtin_amdgcn_mfma_f32_32x32x16_bf16(al, bh, acc[mt], 0, 0, 0);
        acc[mt] = __builtin_amdgcn_mfma_f32_32x32x16_bf16(ah, bl, acc[mt], 0, 0, 0);
      }
    }
    float xxn = xx[n];
    #pragma unroll
    for (int mt = 0; mt < 7; ++mt)
      #pragma unroll
      for (int i = 0; i < 16; ++i) {
        int m = mt * 32 + (i & 3) + 8 * (i >> 2) + 4 * hi;
        float d = 2.f * acc[mt][i] - xx[m] - xxn;
        topk_insert(d, m, tv, ti);
      }
  }
  __syncthreads();
  float* LV = (float*)XH;
  int* LI = (int*)XM;
  if (w < 7) {
    int slot = (w * 64 + lane) * KNN;
    #pragma unroll
    for (int k = 0; k < KNN; ++k) { LV[slot + k] = tv[k]; LI[slot + k] = ti[k]; }
  }
  __syncthreads();
  if (w < 7 && hi == 0) {
    int n = w * 32 + lc;
    if (n < NPT) {
      int sa = (w * 64 + lane) * KNN, sb = sa + 32 * KNN;
      int a = 0, bq = 0;
      int* ob = idxout + ((size_t)b * NPT + n) * KNN;
      #pragma unroll
      for (int k = 0; k < KNN; ++k) {
        float va = LV[sa + a], vb = LV[sb + bq];
        int ia = LI[sa + a], ic = LI[sb + bq];
        bool ta = (va > vb) || (va == vb && ia < ic);
        ob[k] = ta ? ia : ic;
        if (ta) ++a; else ++bq;
      }
    }
  }
}

// Fused edge conv. WBF16: also emit h/l bf16 in w5-ready [b][c/8][col224][8]
// layout (pads zeroed). WF32: emit the fp32 slab (skippable for layer 4 when
// only w5 consumes it).
template<int CIN, bool WBF16, bool WF32>
__global__ __launch_bounds__(256, 2) void k_conv_fused(const float* __restrict__ x, int ldb,
    const float* __restrict__ W, const int* __restrict__ idxb, float* __restrict__ xout,
    unsigned short* __restrict__ xch, unsigned short* __restrict__ xcl, int cbase) {
  constexpr int NPAD = 224;
  constexpr int DBS = 224;
  constexpr int REGION = 64 * DBS;
  __shared__ __align__(16) float smem[REGION + CIN * 64];
  __shared__ unsigned short idxl[NPT * KNN];
  float* xl = smem;
  float* db = smem;
  float* wl = smem + REGION;
  int b = blockIdx.x, og = blockIdx.y;
  const float* xb = x + (size_t)b * ldb;
  for (int i = threadIdx.x; i < CIN * NPAD; i += 256) {
    int c = i / NPAD, n = i - c * NPAD;
    xl[i] = (n < NPT) ? xb[c * NPT + n] : 0.f;
  }
  for (int i = threadIdx.x; i < 64 * CIN; i += 256) {
    int rl = i & 63, c = i >> 6;
    int o = og * 32 + (rl & 31);
    float wv = (rl < 32) ? W[o * 2 * CIN + c]
                         : (W[o * 2 * CIN + CIN + c] - W[o * 2 * CIN + c]);
    wl[c * 64 + rl] = wv;
  }
  for (int i = threadIdx.x; i < NPT * KNN; i += 256)
    idxl[i] = (unsigned short)idxb[(size_t)b * NPT * KNN + i];
  __syncthreads();
  int rq = threadIdx.x & 15, nq = threadIdx.x >> 4;
  int gv[4]; bool gok[4];
  #pragma unroll
  for (int j = 0; j < 4; ++j) { int g = nq + j * 16; gok[j] = g < 55; gv[j] = (g < 55 ? g : 54) * 4; }
  f4 acc[4][4];
  #pragma unroll
  for (int j = 0; j < 4; ++j)
    #pragma unroll
    for (int i2 = 0; i2 < 4; ++i2) acc[j][i2] = (f4){0.f, 0.f, 0.f, 0.f};
  #pragma unroll 2
  for (int c = 0; c < CIN; ++c) {
    f4 wv = *(const f4*)&wl[c * 64 + rq * 4];
    #pragma unroll
    for (int j = 0; j < 4; ++j) {
      f4 xv = *(const f4*)&xl[c * NPAD + gv[j]];
      acc[j][0] += wv.x * xv; acc[j][1] += wv.y * xv;
      acc[j][2] += wv.z * xv; acc[j][3] += wv.w * xv;
    }
  }
  __syncthreads();
  #pragma unroll
  for (int j = 0; j < 4; ++j) {
    if (gok[j]) {
      #pragma unroll
      for (int i2 = 0; i2 < 4; ++i2)
        *(f4*)&db[(rq * 4 + i2) * DBS + gv[j]] = acc[j][i2];
    }
  }
  __syncthreads();
  int o0 = og * 32;
  for (int i = threadIdx.x; i < 32 * 224; i += 256) {
    int ol = i / 224, n = i - ol * 224;
    unsigned short h = 0, l = 0;
    if (n < NPT) {
      const float* drow = &db[ol * DBS];
      const unsigned short* ib = &idxl[n * KNN];
      float mx = -1e30f;
      #pragma unroll
      for (int k = 0; k < KNN; ++k) mx = fmaxf(mx, drow[ib[k]]);
      float v = mx + db[(32 + ol) * DBS + n];
      v = (v >= 0.f) ? v : 0.2f * v;
      if (WF32) xout[((size_t)b * XCCH + o0 + ol) * NPT + n] = v;
      if (WBF16) bfsplit(v, h, l);
    }
    if (WBF16) {
      int c = cbase + o0 + ol;
      size_t off = (((size_t)b * 32 + (c >> 3)) * 224 + n) * 8 + (c & 7);
      xch[off] = h;
      xcl[off] = l;
    }
  }
}

// W5 GEMM, pre-split path: B staging is a CONTIGUOUS bf16 memcpy (global
// layout == LDS layout [g][col224][8]) -> zero split work, zero conflicts,
// 28KB LDS. MFMA k16 order ascending, identical to fallback -> bitwise-same p.
__global__ __launch_bounds__(256) void k_w5_mfma_ps(
    const unsigned short* __restrict__ xch, const unsigned short* __restrict__ xcl,
    const unsigned short* __restrict__ Wh, const unsigned short* __restrict__ Wl,
    const float* __restrict__ g5, const float* __restrict__ b5, const float* __restrict__ m5,
    const float* __restrict__ v5, float* __restrict__ p) {
  __shared__ __align__(16) unsigned short XH[4 * 224 * 8];   // 14KB
  __shared__ __align__(16) unsigned short XL[4 * 224 * 8];
  int d = blockIdx.x;
  int b = (d & 7) * 95 + (d >> 5);
  int rg = (d >> 3) & 3;
  if (b >= NB) return;
  int lane = threadIdx.x & 63, w = threadIdx.x >> 6;
  f16v acc[7];
  #pragma unroll
  for (int t = 0; t < 7; ++t)
    #pragma unroll
    for (int i = 0; i < 16; ++i) acc[t][i] = 0.f;

  int r = rg * 128 + w * 32 + (lane & 31);
  int khalf = (lane >> 5) * 8;
  const u4v* srcH = (const u4v*)(xch + (size_t)b * 57344);   // 32*224*8
  const u4v* srcL = (const u4v*)(xcl + (size_t)b * 57344);
  u4v* dH = (u4v*)XH;
  u4v* dL = (u4v*)XL;

  for (int cb = 0; cb < 8; ++cb) {
    if (cb) __syncthreads();
    const u4v* sH = srcH + cb * 896;     // 4 granules x 224 x 8 bf16 = 896 u4
    const u4v* sL = srcL + cb * 896;
    for (int i = threadIdx.x; i < 896; i += 256) {
      dH[i] = sH[i];
      dL[i] = sL[i];
    }
    __syncthreads();
    #pragma unroll
    for (int ks = 0; ks < 2; ++ks) {
      int kg = cb * 32 + ks * 16 + khalf;
      int g = ks * 2 + (lane >> 5);
      bf8v ah = *(const bf8v*)&Wh[(size_t)r * 256 + kg];
      bf8v al = *(const bf8v*)&Wl[(size_t)r * 256 + kg];
      #pragma unroll
      for (int t = 0; t < 7; ++t) {
        int col = t * 32 + (lane & 31);
        bf8v bh = *(const bf8v*)&XH[g * 1792 + col * 8];
        bf8v bl = *(const bf8v*)&XL[g * 1792 + col * 8];
        acc[t] = __builtin_amdgcn_mfma_f32_32x32x16_bf16(ah, bh, acc[t], 0, 0, 0);
        acc[t] = __builtin_amdgcn_mfma_f32_32x32x16_bf16(al, bh, acc[t], 0, 0, 0);
        acc[t] = __builtin_amdgcn_mfma_f32_32x32x16_bf16(ah, bl, acc[t], 0, 0, 0);
      }
    }
  }
  int rbase = rg * 128 + w * 32 + 4 * (lane >> 5);
  int lc = lane & 31;
  #pragma unroll
  for (int i = 0; i < 16; ++i) {
    int row = rbase + (i & 3) + 8 * (i >> 2);
    float a = g5[row] * rsqrtf(v5[row] + 1e-5f);
    float dq = b5[row] - m5[row] * a;
    float mx = -1e30f, sm = 0.f;
    #pragma unroll
    for (int t = 0; t < 7; ++t) {
      bool valid = (t < 6) || (lc < 28);
      float hv = a * acc[t][i] + dq;
      float lv = (hv >= 0.f) ? hv : 0.2f * hv;
      if (valid) { mx = fmaxf(mx, lv); sm += lv; }
    }
    #pragma unroll
    for (int m_ = 1; m_ <= 16; m_ <<= 1) {
      mx = fmaxf(mx, __shfl_xor(mx, m_));
      sm += __shfl_xor(sm, m_);
    }
    if (lc == 0) {
      p[(size_t)b * 1024 + row] = mx;
      p[(size_t)b * 1024 + 512 + row] = sm * (1.f / NPT);
    }
  }
}

// W5 GEMM fallback (exact R6 form, 281us known): inline split staging, KP=72.
#define KP 72
__global__ __launch_bounds__(256) void k_w5_mfma(const float* __restrict__ xc,
    const unsigned short* __restrict__ Wh, const unsigned short* __restrict__ Wl,
    const float* __restrict__ g5, const float* __restrict__ b5, const float* __restrict__ m5,
    const float* __restrict__ v5, float* __restrict__ p) {
  __shared__ __align__(16) unsigned short XH[224 * KP];
  __shared__ __align__(16) unsigned short XL[224 * KP];
  int d = blockIdx.x;
  int b = (d & 7) * 95 + (d >> 5);
  int rg = (d >> 3) & 3;
  if (b >= NB) return;
  int lane = threadIdx.x & 63, w = threadIdx.x >> 6;
  f16v acc[7];
  #pragma unroll
  for (int t = 0; t < 7; ++t)
    #pragma unroll
    for (int i = 0; i < 16; ++i) acc[t][i] = 0.f;

  int r = rg * 128 + w * 32 + (lane & 31);
  int khalf = (lane >> 5) * 8;

  for (int cb = 0; cb < 4; ++cb) {
    if (cb) __syncthreads();
    for (int i = threadIdx.x; i < 32 * NPT; i += 256) {
      int cp = i / NPT;
      int n = i - cp * NPT;
      int c0 = cp * 2;
      const float* src = &xc[((size_t)b * XCCH + cb * 64 + c0) * NPT + n];
      float x0 = src[0];
      float x1 = src[NPT];
      unsigned short h0, l0, h1, l1;
      bfsplit(x0, h0, l0); bfsplit(x1, h1, l1);
      ((unsigned*)XH)[(n * KP + c0) >> 1] = (unsigned)h0 | ((unsigned)h1 << 16);
      ((unsigned*)XL)[(n * KP + c0) >> 1] = (unsigned)l0 | ((unsigned)l1 << 16);
    }
    for (int i = threadIdx.x; i < 4 * 32; i += 256) {
      int n = NPT + (i >> 5); int cd = i & 31;
      ((unsigned*)XH)[n * (KP / 2) + cd] = 0u;
      ((unsigned*)XL)[n * (KP / 2) + cd] = 0u;
    }
    __syncthreads();
    #pragma unroll
    for (int ks = 0; ks < 4; ++ks) {
      int kg = cb * 64 + ks * 16 + khalf;
      int kl = ks * 16 + khalf;
      bf8v ah = *(const bf8v*)&Wh[(size_t)r * 256 + kg];
      bf8v al = *(const bf8v*)&Wl[(size_t)r * 256 + kg];
      #pragma unroll
      for (int t = 0; t < 7; ++t) {
        int col = t * 32 + (lane & 31);
        bf8v bh = *(const bf8v*)&XH[col * KP + kl];
        bf8v bl = *(const bf8v*)&XL[col * KP + kl];
        acc[t] = __builtin_amdgcn_mfma_f32_32x32x16_bf16(ah, bh, acc[t], 0, 0, 0);
        acc[t] = __builtin_amdgcn_mfma_f32_32x32x16_bf16(al, bh, acc[t], 0, 0, 0);
        acc[t] = __builtin_amdgcn_mfma_f32_32x32x16_bf16(ah, bl, acc[t], 0, 0, 0);
      }
    }
  }
  int rbase = rg * 128 + w * 32 + 4 * (lane >> 5);
  int lc = lane & 31;
  #pragma unroll
  for (int i = 0; i < 16; ++i) {
    int row = rbase + (i & 3) + 8 * (i >> 2);
    float a = g5[row] * rsqrtf(v5[row] + 1e-5f);
    float dq = b5[row] - m5[row] * a;
    float mx = -1e30f, sm = 0.f;
    #pragma unroll
    for (int t = 0; t < 7; ++t) {
      bool valid = (t < 6) || (lc < 28);
      float hv = a * acc[t][i] + dq;
      float lv = (hv >= 0.f) ? hv : 0.2f * hv;
      if (valid) { mx = fmaxf(mx, lv); sm += lv; }
    }
    #pragma unroll
    for (int m_ = 1; m_ <= 16; m_ <<= 1) {
      mx = fmaxf(mx, __shfl_xor(mx, m_));
      sm += __shfl_xor(sm, m_);
    }
    if (lc == 0) {
      p[(size_t)b * 1024 + row] = mx;
      p[(size_t)b * 1024 + 512 + row] = sm * (1.f / NPT);
    }
  }
}

// out[b][o] = in[b][:] . Wt[o][:]  (+ bn+leaky | + bias)
template<int ON, bool FUSE>
__global__ __launch_bounds__(256) void k_fc(const float* __restrict__ in, const float* __restrict__ Wt,
    const float* __restrict__ q0, const float* __restrict__ q1, const float* __restrict__ q2,
    const float* __restrict__ q3, float* __restrict__ out, int ostride) {
  __shared__ __align__(16) float il[32 * 68];
  __shared__ __align__(16) float wl[32 * 68];
  int b0 = blockIdx.x * 64, o0 = blockIdx.y * 64;
  int oq = threadIdx.x & 15, bq = threadIdx.x >> 4;
  f4 acc[4];
  #pragma unroll
  for (int i2 = 0; i2 < 4; ++i2) acc[i2] = (f4){0.f, 0.f, 0.f, 0.f};
  for (int cb = 0; cb < 32; ++cb) {
    if (cb) __syncthreads();
    for (int i = threadIdx.x; i < 2048; i += 256) {
      int c = i & 31, bb = i >> 5;
      il[c * 68 + bb] = (b0 + bb < NB) ? in[(b0 + bb) * 1024 + cb * 32 + c] : 0.f;
    }
    for (int i = threadIdx.x; i < 2048; i += 256) {
      int c = i & 31, ol = i >> 5;
      wl[c * 68 + ol] = (o0 + ol < ON) ? Wt[(o0 + ol) * 1024 + cb * 32 + c] : 0.f;
    }
    __syncthreads();
    #pragma unroll
    for (int c = 0; c < 32; ++c) {
      f4 wv = *(const f4*)&wl[c * 68 + oq * 4];
      f4 iv = *(const f4*)&il[c * 68 + bq * 4];
      acc[0] += wv.x * iv; acc[1] += wv.y * iv; acc[2] += wv.z * iv; acc[3] += wv.w * iv;
    }
  }
  #pragma unroll
  for (int i2 = 0; i2 < 4; ++i2) {
    int o = o0 + oq * 4 + i2;
    if (o >= ON) continue;
    float A = 1.f, Dv = 0.f;
    if (FUSE) { float a = q0[o] * rsqrtf(q3[o] + 1e-5f); A = a; Dv = q1[o] - q2[o] * a; }
    else { Dv = q0[o]; }
    #pragma unroll
    for (int jj = 0; jj < 4; ++jj) {
      int bb = b0 + bq * 4 + jj;
      if (bb < NB) {
        float v = acc[i2][jj];
        if (FUSE) { v = A * v + Dv; v = (v >= 0.f) ? v : 0.2f * v; }
        else { v = v + Dv; }
        out[(size_t)bb * ostride + o] = v;
      }
    }
  }
}

extern "C" void kernel_launch(void* const* d_in, const int* in_sizes, int n_in,
                              void* d_out, int out_size, void* d_ws, size_t ws_size,
                              hipStream_t stream) {
  const float* input = (const float*)d_in[0];
  const float* W1 = (const float*)d_in[1];
  const float* W2 = (const float*)d_in[2];
  const float* W3 = (const float*)d_in[3];
  const float* W4 = (const float*)d_in[4];
  const float* W5 = (const float*)d_in[5];
  const float* g5 = (const float*)d_in[6];
  const float* b5 = (const float*)d_in[7];
  const float* m5 = (const float*)d_in[8];
  const float* v5 = (const float*)d_in[9];
  const float* Wl1 = (const float*)d_in[10];
  const float* g6 = (const float*)d_in[11];
  const float* b6 = (const float*)d_in[12];
  const float* m6 = (const float*)d_in[13];
  const float* v6 = (const float*)d_in[14];
  const float* Wl2 = (const float*)d_in[15];
  const float* bl2 = (const float*)d_in[16];

  // base workspace layout (floats): ~186.4 MB
  float* w = (float*)d_ws;
  float* x0 = w;                          //   500,940
  float* xc = x0 + 500940;                //  42,746,880
  float* p  = xc + 42746880;              //     777,216
  float* z  = p  + 777216;                //     777,216
  int* idxb = (int*)(z + 777216);         //   1,669,800 ints
  unsigned short* wh = (unsigned short*)(w + 46472052);  // 131,072 bf16
  unsigned short* wlo = wh + 131072;
  // pre-split path extension: 2 x 43,524,096 bf16 = 174.1 MB
  unsigned short* xch = wlo + 131072;     // [b][32][224][8]
  unsigned short* xcl = xch + 43524096;
  size_t need = (size_t)(xcl + 43524096 - (unsigned short*)d_ws) * 2;
  bool ps = ws_size >= need;

  k_transpose<<<1957, 256, 0, stream>>>(input, x0);
  k_w5split<<<512, 256, 0, stream>>>(W5, wh, wlo);

  k_knn3<<<759, 256, 0, stream>>>(x0, 3 * NPT, idxb);

  if (ps) {
    k_conv_fused<3, true, true><<<dim3(759, 1), 256, 0, stream>>>(x0, 3 * NPT, W1, idxb, xc, xch, xcl, 0);
    k_knn_mfma<32><<<759, 512, 0, stream>>>(xc, LDXC, idxb);
    k_conv_fused<32, true, true><<<dim3(759, 1), 256, 0, stream>>>(xc, LDXC, W2, idxb, xc + 32 * NPT, xch, xcl, 32);
    k_knn_mfma<32><<<759, 512, 0, stream>>>(xc + 32 * NPT, LDXC, idxb);
    k_conv_fused<32, true, true><<<dim3(759, 2), 256, 0, stream>>>(xc + 32 * NPT, LDXC, W3, idxb, xc + 64 * NPT, xch, xcl, 64);
    k_knn_mfma<64><<<759, 512, 0, stream>>>(xc + 64 * NPT, LDXC, idxb);
    k_conv_fused<64, true, false><<<dim3(759, 4), 256, 0, stream>>>(xc + 64 * NPT, LDXC, W4, idxb, xc + 128 * NPT, xch, xcl, 128);
    k_w5_mfma_ps<<<3040, 256, 0, stream>>>(xch, xcl, wh, wlo, g5, b5, m5, v5, p);
  } else {
    k_conv_fused<3, false, true><<<dim3(759, 1), 256, 0, stream>>>(x0, 3 * NPT, W1, idxb, xc, xch, xcl, 0);
    k_knn_mfma<32><<<759, 512, 0, stream>>>(xc, LDXC, idxb);
    k_conv_fused<32, false, true><<<dim3(759, 1), 256, 0, stream>>>(xc, LDXC, W2, idxb, xc + 32 * NPT, xch, xcl, 32);
    k_knn_mfma<32><<<759, 512, 0, stream>>>(xc + 32 * NPT, LDXC, idxb);
    k_conv_fused<32, false, true><<<dim3(759, 2), 256, 0, stream>>>(xc + 32 * NPT, LDXC, W3, idxb, xc + 64 * NPT, xch, xcl, 64);
    k_knn_mfma<64><<<759, 512, 0, stream>>>(xc + 64 * NPT, LDXC, idxb);
    k_conv_fused<64, false, true><<<dim3(759, 4), 256, 0, stream>>>(xc + 64 * NPT, LDXC, W4, idxb, xc + 128 * NPT, xch, xcl, 128);
    k_w5_mfma<<<3040, 256, 0, stream>>>(xc, wh, wlo, g5, b5, m5, v5, p);
  }

  k_fc<1024, true><<<dim3(12, 16), 256, 0, stream>>>(p, Wl1, g6, b6, m6, v6, z, 1024);
  k_fc<380, false><<<dim3(12, 6), 256, 0, stream>>>(z, Wl2, bl2, bl2, bl2, bl2, (float*)d_out, 380);
}

// Round 11
// 1713.741 us; speedup vs baseline: 1.1091x; 1.0041x over previous
//
#include <hip/hip_runtime.h>
#include <math.h>

#define NB 759
#define NPT 220
#define KNN 10
#define XCCH 256
#define LDXC (XCCH * NPT)

typedef float f4 __attribute__((ext_vector_type(4)));
typedef float f16v __attribute__((ext_vector_type(16)));
typedef short bf8v __attribute__((ext_vector_type(8)));   // 8 bf16 in 4 VGPRs
typedef unsigned u4v __attribute__((ext_vector_type(4))); // 16B copy unit

// ---- bf16 split helpers (RNE). h+m+l reconstructs fp32 ~exactly (24=3x8 bits).
__device__ inline unsigned short bfh(float x) {
  unsigned u = __float_as_uint(x);
  unsigned r = u + 0x7FFFu + ((u >> 16) & 1u);
  return (unsigned short)(r >> 16);
}
__device__ inline float bff(unsigned short h) {
  return __uint_as_float(((unsigned)h) << 16);
}
__device__ inline void bfsplit(float x, unsigned short& h, unsigned short& l) {
  h = bfh(x);
  l = bfh(x - bff(h));
}

// input (B,N,3) -> x0 (B,3,N)
__global__ __launch_bounds__(256) void k_transpose(const float* __restrict__ in, float* __restrict__ x0) {
  int i = blockIdx.x * 256 + threadIdx.x;
  if (i >= NB * 3 * NPT) return;
  int n = i % NPT; int t = i / NPT; int c = t % 3; int b = t / 3;
  x0[i] = in[(b * NPT + n) * 3 + c];
}

// W5 (512x256 fp32) -> Wh, Wl (bf16)
__global__ __launch_bounds__(256) void k_w5split(const float* __restrict__ W5,
    unsigned short* __restrict__ Wh, unsigned short* __restrict__ Wl) {
  int i = blockIdx.x * 256 + threadIdx.x;
  if (i >= 512 * 256) return;
  bfsplit(W5[i], Wh[i], Wl[i]);
}

__device__ inline void topk_insert(float d, int m, float* tv, int* ti) {
  if (d > tv[KNN - 1]) {      // strict >: ties keep earlier index (matches lax.top_k set)
    tv[KNN - 1] = d; ti[KNN - 1] = m;
    #pragma unroll
    for (int j = KNN - 1; j >= 1; --j) {
      if (tv[j] > tv[j - 1]) {
        float tf = tv[j - 1]; tv[j - 1] = tv[j]; tv[j] = tf;
        int tq = ti[j - 1]; ti[j - 1] = ti[j]; ti[j] = tq;
      } else break;
    }
  }
}

// kNN for C=3: cheap VALU version
__global__ __launch_bounds__(256) void k_knn3(const float* __restrict__ x, int ldb,
                                              int* __restrict__ idxout) {
  __shared__ __align__(16) float xl[NPT * 4];
  __shared__ float xx[NPT];
  int b = blockIdx.x;
  const float* xb = x + (size_t)b * ldb;
  for (int i = threadIdx.x; i < NPT; i += 256) {
    f4 v; v.x = xb[i]; v.y = xb[NPT + i]; v.z = xb[2 * NPT + i]; v.w = 0.f;
    *(f4*)&xl[i * 4] = v;
    xx[i] = v.x * v.x + v.y * v.y + v.z * v.z;
  }
  __syncthreads();
  int n = threadIdx.x;
  if (n >= NPT) return;
  f4 xn = *(const f4*)&xl[n * 4];
  float xxn = xx[n];
  float tv[KNN]; int ti[KNN];
  #pragma unroll
  for (int k = 0; k < KNN; ++k) { tv[k] = -1e30f; ti[k] = 0; }
  for (int m = 0; m < NPT; ++m) {
    f4 v = *(const f4*)&xl[m * 4];
    float dot = xn.x * v.x + xn.y * v.y + xn.z * v.z;
    topk_insert(2.f * dot - xxn - xx[m], m, tv, ti);
  }
  int* ib = idxout + ((size_t)b * NPT + n) * KNN;
  #pragma unroll
  for (int k = 0; k < KNN; ++k) ib[k] = ti[k];
}

// kNN via MFMA Gram matrix, 3-way bf16 split (6 products ~ fp32-exact).
template<int C>
__global__ __launch_bounds__(512) void k_knn_mfma(const float* __restrict__ x, int ldb,
                                                  int* __restrict__ idxout) {
  constexpr int KPG = C + 8;
  constexpr int SW = (C / 16) - 1;
  __shared__ __align__(16) unsigned short XH[224 * KPG];
  __shared__ __align__(16) unsigned short XM[224 * KPG];
  __shared__ __align__(16) unsigned short XL[224 * KPG];
  __shared__ float xx[224];
  int b = blockIdx.x;
  const float* xb = x + (size_t)b * ldb;
  for (int i = threadIdx.x; i < C * 224; i += 512) {
    int c = i / 224, m = i - c * 224;
    float v = (m < NPT) ? xb[c * NPT + m] : 0.f;
    unsigned short h = bfh(v);
    float r1 = v - bff(h);
    unsigned short mm = bfh(r1);
    unsigned short l = bfh(r1 - bff(mm));
    int cs = c ^ ((m & SW) << 4);
    XH[m * KPG + cs] = h; XM[m * KPG + cs] = mm; XL[m * KPG + cs] = l;
  }
  for (int m = threadIdx.x; m < 224; m += 512) {
    float s = 0.f;
    if (m < NPT) {
      for (int c = 0; c < C; ++c) { float v = xb[c * NPT + m]; s += v * v; }
    } else s = 1e30f;
    xx[m] = s;
  }
  __syncthreads();
  int w = threadIdx.x >> 6;
  int lane = threadIdx.x & 63;
  int lc = lane & 31, hi = lane >> 5;
  float tv[KNN]; int ti[KNN];
  #pragma unroll
  for (int k = 0; k < KNN; ++k) { tv[k] = -1e30f; ti[k] = 0; }
  if (w < 7) {
    int n = w * 32 + lc;
    f16v acc[7];
    #pragma unroll
    for (int mt = 0; mt < 7; ++mt)
      #pragma unroll
      for (int i = 0; i < 16; ++i) acc[mt][i] = 0.f;
    #pragma unroll
    for (int ks = 0; ks < C / 16; ++ks) {
      int kb = ks * 16 + hi * 8;
      int nsw = kb ^ ((n & SW) << 4);
      bf8v bh = *(const bf8v*)&XH[n * KPG + nsw];
      bf8v bm = *(const bf8v*)&XM[n * KPG + nsw];
      bf8v bl = *(const bf8v*)&XL[n * KPG + nsw];
      #pragma unroll
      for (int mt = 0; mt < 7; ++mt) {
        int mr = mt * 32 + lc;
        int msw = kb ^ ((mr & SW) << 4);
        bf8v ah = *(const bf8v*)&XH[mr * KPG + msw];
        bf8v am = *(const bf8v*)&XM[mr * KPG + msw];
        bf8v al = *(const bf8v*)&XL[mr * KPG + msw];
        acc[mt] = __builtin_amdgcn_mfma_f32_32x32x16_bf16(ah, bh, acc[mt], 0, 0, 0);
        acc[mt] = __builtin_amdgcn_mfma_f32_32x32x16_bf16(am, bh, acc[mt], 0, 0, 0);
        acc[mt] = __builtin_amdgcn_mfma_f32_32x32x16_bf16(ah, bm, acc[mt], 0, 0, 0);
        acc[mt] = __builtin_amdgcn_mfma_f32_32x32x16_bf16(am, bm, acc[mt], 0, 0, 0);
        acc[mt] = __builtin_amdgcn_mfma_f32_32x32x16_bf16(al, bh, acc[mt], 0, 0, 0);
        acc[mt] = __builtin_amdgcn_mfma_f32_32x32x16_bf16(ah, bl, acc[mt], 0, 0, 0);
      }
    }
    float xxn = xx[n];
    #pragma unroll
    for (int mt = 0; mt < 7; ++mt)
      #pragma unroll
      for (int i = 0; i < 16; ++i) {
        int m = mt * 32 + (i & 3) + 8 * (i >> 2) + 4 * hi;
        float d = 2.f * acc[mt][i] - xx[m] - xxn;
        topk_insert(d, m, tv, ti);
      }
  }
  __syncthreads();
  float* LV = (float*)XH;
  int* LI = (int*)XM;
  if (w < 7) {
    int slot = (w * 64 + lane) * KNN;
    #pragma unroll
    for (int k = 0; k < KNN; ++k) { LV[slot + k] = tv[k]; LI[slot + k] = ti[k]; }
  }
  __syncthreads();
  if (w < 7 && hi == 0) {
    int n = w * 32 + lc;
    if (n < NPT) {
      int sa = (w * 64 + lane) * KNN, sb = sa + 32 * KNN;
      int a = 0, bq = 0;
      int* ob = idxout + ((size_t)b * NPT + n) * KNN;
      #pragma unroll
      for (int k = 0; k < KNN; ++k) {
        float va = LV[sa + a], vb = LV[sb + bq];
        int ia = LI[sa + a], ic = LI[sb + bq];
        bool ta = (va > vb) || (va == vb && ia < ic);
        ob[k] = ta ? ia : ic;
        if (ta) ++a; else ++bq;
      }
    }
  }
}

// Fused edge conv. R11: 1-D grid with XCD swizzle — all OG og-blocks of one
// batch land consecutively on the SAME XCD so the x slab + idx list hit L2.
// Work/order per block unchanged -> bitwise-identical output to R10.
template<int CIN, int OG, bool WBF16, bool WF32>
__global__ __launch_bounds__(256, 2) void k_conv_fused(const float* __restrict__ x, int ldb,
    const float* __restrict__ W, const int* __restrict__ idxb, float* __restrict__ xout,
    unsigned short* __restrict__ xch, unsigned short* __restrict__ xcl, int cbase) {
  constexpr int NPAD = 224;
  constexpr int DBS = 224;
  constexpr int REGION = 64 * DBS;
  __shared__ __align__(16) float smem[REGION + CIN * 64];
  __shared__ unsigned short idxl[NPT * KNN];
  float* xl = smem;
  float* db = smem;
  float* wl = smem + REGION;
  int d = blockIdx.x;
  int b, og;
  if (OG == 4)      { b = (d & 7) * 95 + (d >> 5); og = (d >> 3) & 3; }
  else if (OG == 2) { b = (d & 7) * 95 + (d >> 4); og = (d >> 3) & 1; }
  else              { b = d; og = 0; }
  if (b >= NB) return;
  const float* xb = x + (size_t)b * ldb;
  for (int i = threadIdx.x; i < CIN * NPAD; i += 256) {
    int c = i / NPAD, n = i - c * NPAD;
    xl[i] = (n < NPT) ? xb[c * NPT + n] : 0.f;
  }
  for (int i = threadIdx.x; i < 64 * CIN; i += 256) {
    int rl = i & 63, c = i >> 6;
    int o = og * 32 + (rl & 31);
    float wv = (rl < 32) ? W[o * 2 * CIN + c]
                         : (W[o * 2 * CIN + CIN + c] - W[o * 2 * CIN + c]);
    wl[c * 64 + rl] = wv;
  }
  for (int i = threadIdx.x; i < NPT * KNN; i += 256)
    idxl[i] = (unsigned short)idxb[(size_t)b * NPT * KNN + i];
  __syncthreads();
  int rq = threadIdx.x & 15, nq = threadIdx.x >> 4;
  int gv[4]; bool gok[4];
  #pragma unroll
  for (int j = 0; j < 4; ++j) { int g = nq + j * 16; gok[j] = g < 55; gv[j] = (g < 55 ? g : 54) * 4; }
  f4 acc[4][4];
  #pragma unroll
  for (int j = 0; j < 4; ++j)
    #pragma unroll
    for (int i2 = 0; i2 < 4; ++i2) acc[j][i2] = (f4){0.f, 0.f, 0.f, 0.f};
  #pragma unroll 2
  for (int c = 0; c < CIN; ++c) {
    f4 wv = *(const f4*)&wl[c * 64 + rq * 4];
    #pragma unroll
    for (int j = 0; j < 4; ++j) {
      f4 xv = *(const f4*)&xl[c * NPAD + gv[j]];
      acc[j][0] += wv.x * xv; acc[j][1] += wv.y * xv;
      acc[j][2] += wv.z * xv; acc[j][3] += wv.w * xv;
    }
  }
  __syncthreads();
  #pragma unroll
  for (int j = 0; j < 4; ++j) {
    if (gok[j]) {
      #pragma unroll
      for (int i2 = 0; i2 < 4; ++i2)
        *(f4*)&db[(rq * 4 + i2) * DBS + gv[j]] = acc[j][i2];
    }
  }
  __syncthreads();
  int o0 = og * 32;
  for (int i = threadIdx.x; i < 32 * 224; i += 256) {
    int ol = i / 224, n = i - ol * 224;
    unsigned short h = 0, l = 0;
    if (n < NPT) {
      const float* drow = &db[ol * DBS];
      const unsigned short* ib = &idxl[n * KNN];
      float mx = -1e30f;
      #pragma unroll
      for (int k = 0; k < KNN; ++k) mx = fmaxf(mx, drow[ib[k]]);
      float v = mx + db[(32 + ol) * DBS + n];
      v = (v >= 0.f) ? v : 0.2f * v;
      if (WF32) xout[((size_t)b * XCCH + o0 + ol) * NPT + n] = v;
      if (WBF16) bfsplit(v, h, l);
    }
    if (WBF16) {
      int c = cbase + o0 + ol;
      size_t off = (((size_t)b * 32 + (c >> 3)) * 224 + n) * 8 + (c & 7);
      xch[off] = h;
      xcl[off] = l;
    }
  }
}

// W5 GEMM, pre-split path: B staging is a CONTIGUOUS bf16 memcpy (global
// layout == LDS layout [g][col224][8]) -> zero split work, zero conflicts.
__global__ __launch_bounds__(256) void k_w5_mfma_ps(
    const unsigned short* __restrict__ xch, const unsigned short* __restrict__ xcl,
    const unsigned short* __restrict__ Wh, const unsigned short* __restrict__ Wl,
    const float* __restrict__ g5, const float* __restrict__ b5, const float* __restrict__ m5,
    const float* __restrict__ v5, float* __restrict__ p) {
  __shared__ __align__(16) unsigned short XH[4 * 224 * 8];   // 14KB
  __shared__ __align__(16) unsigned short XL[4 * 224 * 8];
  int d = blockIdx.x;
  int b = (d & 7) * 95 + (d >> 5);
  int rg = (d >> 3) & 3;
  if (b >= NB) return;
  int lane = threadIdx.x & 63, w = threadIdx.x >> 6;
  f16v acc[7];
  #pragma unroll
  for (int t = 0; t < 7; ++t)
    #pragma unroll
    for (int i = 0; i < 16; ++i) acc[t][i] = 0.f;

  int r = rg * 128 + w * 32 + (lane & 31);
  int khalf = (lane >> 5) * 8;
  const u4v* srcH = (const u4v*)(xch + (size_t)b * 57344);   // 32*224*8
  const u4v* srcL = (const u4v*)(xcl + (size_t)b * 57344);
  u4v* dH = (u4v*)XH;
  u4v* dL = (u4v*)XL;

  for (int cb = 0; cb < 8; ++cb) {
    if (cb) __syncthreads();
    const u4v* sH = srcH + cb * 896;
    const u4v* sL = srcL + cb * 896;
    for (int i = threadIdx.x; i < 896; i += 256) {
      dH[i] = sH[i];
      dL[i] = sL[i];
    }
    __syncthreads();
    #pragma unroll
    for (int ks = 0; ks < 2; ++ks) {
      int kg = cb * 32 + ks * 16 + khalf;
      int g = ks * 2 + (lane >> 5);
      bf8v ah = *(const bf8v*)&Wh[(size_t)r * 256 + kg];
      bf8v al = *(const bf8v*)&Wl[(size_t)r * 256 + kg];
      #pragma unroll
      for (int t = 0; t < 7; ++t) {
        int col = t * 32 + (lane & 31);
        bf8v bh = *(const bf8v*)&XH[g * 1792 + col * 8];
        bf8v bl = *(const bf8v*)&XL[g * 1792 + col * 8];
        acc[t] = __builtin_amdgcn_mfma_f32_32x32x16_bf16(ah, bh, acc[t], 0, 0, 0);
        acc[t] = __builtin_amdgcn_mfma_f32_32x32x16_bf16(al, bh, acc[t], 0, 0, 0);
        acc[t] = __builtin_amdgcn_mfma_f32_32x32x16_bf16(ah, bl, acc[t], 0, 0, 0);
      }
    }
  }
  int rbase = rg * 128 + w * 32 + 4 * (lane >> 5);
  int lc = lane & 31;
  #pragma unroll
  for (int i = 0; i < 16; ++i) {
    int row = rbase + (i & 3) + 8 * (i >> 2);
    float a = g5[row] * rsqrtf(v5[row] + 1e-5f);
    float dq = b5[row] - m5[row] * a;
    float mx = -1e30f, sm = 0.f;
    #pragma unroll
    for (int t = 0; t < 7; ++t) {
      bool valid = (t < 6) || (lc < 28);
      float hv = a * acc[t][i] + dq;
      float lv = (hv >= 0.f) ? hv : 0.2f * hv;
      if (valid) { mx = fmaxf(mx, lv); sm += lv; }
    }
    #pragma unroll
    for (int m_ = 1; m_ <= 16; m_ <<= 1) {
      mx = fmaxf(mx, __shfl_xor(mx, m_));
      sm += __shfl_xor(sm, m_);
    }
    if (lc == 0) {
      p[(size_t)b * 1024 + row] = mx;
      p[(size_t)b * 1024 + 512 + row] = sm * (1.f / NPT);
    }
  }
}

// W5 GEMM fallback (exact R6 form): inline split staging, KP=72.
#define KP 72
__global__ __launch_bounds__(256) void k_w5_mfma(const float* __restrict__ xc,
    const unsigned short* __restrict__ Wh, const unsigned short* __restrict__ Wl,
    const float* __restrict__ g5, const float* __restrict__ b5, const float* __restrict__ m5,
    const float* __restrict__ v5, float* __restrict__ p) {
  __shared__ __align__(16) unsigned short XH[224 * KP];
  __shared__ __align__(16) unsigned short XL[224 * KP];
  int d = blockIdx.x;
  int b = (d & 7) * 95 + (d >> 5);
  int rg = (d >> 3) & 3;
  if (b >= NB) return;
  int lane = threadIdx.x & 63, w = threadIdx.x >> 6;
  f16v acc[7];
  #pragma unroll
  for (int t = 0; t < 7; ++t)
    #pragma unroll
    for (int i = 0; i < 16; ++i) acc[t][i] = 0.f;

  int r = rg * 128 + w * 32 + (lane & 31);
  int khalf = (lane >> 5) * 8;

  for (int cb = 0; cb < 4; ++cb) {
    if (cb) __syncthreads();
    for (int i = threadIdx.x; i < 32 * NPT; i += 256) {
      int cp = i / NPT;
      int n = i - cp * NPT;
      int c0 = cp * 2;
      const float* src = &xc[((size_t)b * XCCH + cb * 64 + c0) * NPT + n];
      float x0 = src[0];
      float x1 = src[NPT];
      unsigned short h0, l0, h1, l1;
      bfsplit(x0, h0, l0); bfsplit(x1, h1, l1);
      ((unsigned*)XH)[(n * KP + c0) >> 1] = (unsigned)h0 | ((unsigned)h1 << 16);
      ((unsigned*)XL)[(n * KP + c0) >> 1] = (unsigned)l0 | ((unsigned)l1 << 16);
    }
    for (int i = threadIdx.x; i < 4 * 32; i += 256) {
      int n = NPT + (i >> 5); int cd = i & 31;
      ((unsigned*)XH)[n * (KP / 2) + cd] = 0u;
      ((unsigned*)XL)[n * (KP / 2) + cd] = 0u;
    }
    __syncthreads();
    #pragma unroll
    for (int ks = 0; ks < 4; ++ks) {
      int kg = cb * 64 + ks * 16 + khalf;
      int kl = ks * 16 + khalf;
      bf8v ah = *(const bf8v*)&Wh[(size_t)r * 256 + kg];
      bf8v al = *(const bf8v*)&Wl[(size_t)r * 256 + kg];
      #pragma unroll
      for (int t = 0; t < 7; ++t) {
        int col = t * 32 + (lane & 31);
        bf8v bh = *(const bf8v*)&XH[col * KP + kl];
        bf8v bl = *(const bf8v*)&XL[col * KP + kl];
        acc[t] = __builtin_amdgcn_mfma_f32_32x32x16_bf16(ah, bh, acc[t], 0, 0, 0);
        acc[t] = __builtin_amdgcn_mfma_f32_32x32x16_bf16(al, bh, acc[t], 0, 0, 0);
        acc[t] = __builtin_amdgcn_mfma_f32_32x32x16_bf16(ah, bl, acc[t], 0, 0, 0);
      }
    }
  }
  int rbase = rg * 128 + w * 32 + 4 * (lane >> 5);
  int lc = lane & 31;
  #pragma unroll
  for (int i = 0; i < 16; ++i) {
    int row = rbase + (i & 3) + 8 * (i >> 2);
    float a = g5[row] * rsqrtf(v5[row] + 1e-5f);
    float dq = b5[row] - m5[row] * a;
    float mx = -1e30f, sm = 0.f;
    #pragma unroll
    for (int t = 0; t < 7; ++t) {
      bool valid = (t < 6) || (lc < 28);
      float hv = a * acc[t][i] + dq;
      float lv = (hv >= 0.f) ? hv : 0.2f * hv;
      if (valid) { mx = fmaxf(mx, lv); sm += lv; }
    }
    #pragma unroll
    for (int m_ = 1; m_ <= 16; m_ <<= 1) {
      mx = fmaxf(mx, __shfl_xor(mx, m_));
      sm += __shfl_xor(sm, m_);
    }
    if (lc == 0) {
      p[(size_t)b * 1024 + row] = mx;
      p[(size_t)b * 1024 + 512 + row] = sm * (1.f / NPT);
    }
  }
}

// out[b][o] = in[b][:] . Wt[o][:]  (+ bn+leaky | + bias)
template<int ON, bool FUSE>
__global__ __launch_bounds__(256) void k_fc(const float* __restrict__ in, const float* __restrict__ Wt,
    const float* __restrict__ q0, const float* __restrict__ q1, const float* __restrict__ q2,
    const float* __restrict__ q3, float* __restrict__ out, int ostride) {
  __shared__ __align__(16) float il[32 * 68];
  __shared__ __align__(16) float wl[32 * 68];
  int b0 = blockIdx.x * 64, o0 = blockIdx.y * 64;
  int oq = threadIdx.x & 15, bq = threadIdx.x >> 4;
  f4 acc[4];
  #pragma unroll
  for (int i2 = 0; i2 < 4; ++i2) acc[i2] = (f4){0.f, 0.f, 0.f, 0.f};
  for (int cb = 0; cb < 32; ++cb) {
    if (cb) __syncthreads();
    for (int i = threadIdx.x; i < 2048; i += 256) {
      int c = i & 31, bb = i >> 5;
      il[c * 68 + bb] = (b0 + bb < NB) ? in[(b0 + bb) * 1024 + cb * 32 + c] : 0.f;
    }
    for (int i = threadIdx.x; i < 2048; i += 256) {
      int c = i & 31, ol = i >> 5;
      wl[c * 68 + ol] = (o0 + ol < ON) ? Wt[(o0 + ol) * 1024 + cb * 32 + c] : 0.f;
    }
    __syncthreads();
    #pragma unroll
    for (int c = 0; c < 32; ++c) {
      f4 wv = *(const f4*)&wl[c * 68 + oq * 4];
      f4 iv = *(const f4*)&il[c * 68 + bq * 4];
      acc[0] += wv.x * iv; acc[1] += wv.y * iv; acc[2] += wv.z * iv; acc[3] += wv.w * iv;
    }
  }
  #pragma unroll
  for (int i2 = 0; i2 < 4; ++i2) {
    int o = o0 + oq * 4 + i2;
    if (o >= ON) continue;
    float A = 1.f, Dv = 0.f;
    if (FUSE) { float a = q0[o] * rsqrtf(q3[o] + 1e-5f); A = a; Dv = q1[o] - q2[o] * a; }
    else { Dv = q0[o]; }
    #pragma unroll
    for (int jj = 0; jj < 4; ++jj) {
      int bb = b0 + bq * 4 + jj;
      if (bb < NB) {
        float v = acc[i2][jj];
        if (FUSE) { v = A * v + Dv; v = (v >= 0.f) ? v : 0.2f * v; }
        else { v = v + Dv; }
        out[(size_t)bb * ostride + o] = v;
      }
    }
  }
}

extern "C" void kernel_launch(void* const* d_in, const int* in_sizes, int n_in,
                              void* d_out, int out_size, void* d_ws, size_t ws_size,
                              hipStream_t stream) {
  const float* input = (const float*)d_in[0];
  const float* W1 = (const float*)d_in[1];
  const float* W2 = (const float*)d_in[2];
  const float* W3 = (const float*)d_in[3];
  const float* W4 = (const float*)d_in[4];
  const float* W5 = (const float*)d_in[5];
  const float* g5 = (const float*)d_in[6];
  const float* b5 = (const float*)d_in[7];
  const float* m5 = (const float*)d_in[8];
  const float* v5 = (const float*)d_in[9];
  const float* Wl1 = (const float*)d_in[10];
  const float* g6 = (const float*)d_in[11];
  const float* b6 = (const float*)d_in[12];
  const float* m6 = (const float*)d_in[13];
  const float* v6 = (const float*)d_in[14];
  const float* Wl2 = (const float*)d_in[15];
  const float* bl2 = (const float*)d_in[16];

  // base workspace layout (floats): ~186.4 MB
  float* w = (float*)d_ws;
  float* x0 = w;                          //   500,940
  float* xc = x0 + 500940;                //  42,746,880
  float* p  = xc + 42746880;              //     777,216
  float* z  = p  + 777216;                //     777,216
  int* idxb = (int*)(z + 777216);         //   1,669,800 ints
  unsigned short* wh = (unsigned short*)(w + 46472052);  // 131,072 bf16
  unsigned short* wlo = wh + 131072;
  // pre-split path extension: 2 x 43,524,096 bf16 = 174.1 MB
  unsigned short* xch = wlo + 131072;     // [b][32][224][8]
  unsigned short* xcl = xch + 43524096;
  size_t need = (size_t)(xcl + 43524096 - (unsigned short*)d_ws) * 2;
  bool ps = ws_size >= need;

  k_transpose<<<1957, 256, 0, stream>>>(input, x0);
  k_w5split<<<512, 256, 0, stream>>>(W5, wh, wlo);

  k_knn3<<<759, 256, 0, stream>>>(x0, 3 * NPT, idxb);

  if (ps) {
    k_conv_fused<3, 1, true, true><<<759, 256, 0, stream>>>(x0, 3 * NPT, W1, idxb, xc, xch, xcl, 0);
    k_knn_mfma<32><<<759, 512, 0, stream>>>(xc, LDXC, idxb);
    k_conv_fused<32, 1, true, true><<<759, 256, 0, stream>>>(xc, LDXC, W2, idxb, xc + 32 * NPT, xch, xcl, 32);
    k_knn_mfma<32><<<759, 512, 0, stream>>>(xc + 32 * NPT, LDXC, idxb);
    k_conv_fused<32, 2, true, true><<<1520, 256, 0, stream>>>(xc + 32 * NPT, LDXC, W3, idxb, xc + 64 * NPT, xch, xcl, 64);
    k_knn_mfma<64><<<759, 512, 0, stream>>>(xc + 64 * NPT, LDXC, idxb);
    k_conv_fused<64, 4, true, false><<<3040, 256, 0, stream>>>(xc + 64 * NPT, LDXC, W4, idxb, xc + 128 * NPT, xch, xcl, 128);
    k_w5_mfma_ps<<<3040, 256, 0, stream>>>(xch, xcl, wh, wlo, g5, b5, m5, v5, p);
  } else {
    k_conv_fused<3, 1, false, true><<<759, 256, 0, stream>>>(x0, 3 * NPT, W1, idxb, xc, xch, xcl, 0);
    k_knn_mfma<32><<<759, 512, 0, stream>>>(xc, LDXC, idxb);
    k_conv_fused<32, 1, false, true><<<759, 256, 0, stream>>>(xc, LDXC, W2, idxb, xc + 32 * NPT, xch, xcl, 32);
    k_knn_mfma<32><<<759, 512, 0, stream>>>(xc + 32 * NPT, LDXC, idxb);
    k_conv_fused<32, 2, false, true><<<1520, 256, 0, stream>>>(xc + 32 * NPT, LDXC, W3, idxb, xc + 64 * NPT, xch, xcl, 64);
    k_knn_mfma<64><<<759, 512, 0, stream>>>(xc + 64 * NPT, LDXC, idxb);
    k_conv_fused<64, 4, false, true><<<3040, 256, 0, stream>>>(xc + 64 * NPT, LDXC, W4, idxb, xc + 128 * NPT, xch, xcl, 128);
    k_w5_mfma<<<3040, 256, 0, stream>>>(xc, wh, wlo, g5, b5, m5, v5, p);
  }

  k_fc<1024, true><<<dim3(12, 16), 256, 0, stream>>>(p, Wl1, g6, b6, m6, v6, z, 1024);
  k_fc<380, false><<<dim3(12, 6), 256, 0, stream>>>(z, Wl2, bl2, bl2, bl2, bl2, (float*)d_out, 380);
}

// Round 12
// 1580.522 us; speedup vs baseline: 1.2026x; 1.0843x over previous
//
#include <hip/hip_runtime.h>
#include <math.h>

#define NB 759
#define NPT 220
#define KNN 10
#define XCCH 256
#define LDXC (XCCH * NPT)

typedef float f4 __attribute__((ext_vector_type(4)));
typedef float f16v __attribute__((ext_vector_type(16)));
typedef short bf8v __attribute__((ext_vector_type(8)));   // 8 bf16 in 4 VGPRs
typedef unsigned u4v __attribute__((ext_vector_type(4))); // 16B copy unit

// ---- bf16 split helpers (RNE). h+m+l reconstructs fp32 ~exactly (24=3x8 bits).
__device__ inline unsigned short bfh(float x) {
  unsigned u = __float_as_uint(x);
  unsigned r = u + 0x7FFFu + ((u >> 16) & 1u);
  return (unsigned short)(r >> 16);
}
__device__ inline float bff(unsigned short h) {
  return __uint_as_float(((unsigned)h) << 16);
}
__device__ inline void bfsplit(float x, unsigned short& h, unsigned short& l) {
  h = bfh(x);
  l = bfh(x - bff(h));
}

// input (B,N,3) -> x0 (B,3,N)
__global__ __launch_bounds__(256) void k_transpose(const float* __restrict__ in, float* __restrict__ x0) {
  int i = blockIdx.x * 256 + threadIdx.x;
  if (i >= NB * 3 * NPT) return;
  int n = i % NPT; int t = i / NPT; int c = t % 3; int b = t / 3;
  x0[i] = in[(b * NPT + n) * 3 + c];
}

// W5 (512x256 fp32) -> Wh, Wl (bf16)
__global__ __launch_bounds__(256) void k_w5split(const float* __restrict__ W5,
    unsigned short* __restrict__ Wh, unsigned short* __restrict__ Wl) {
  int i = blockIdx.x * 256 + threadIdx.x;
  if (i >= 512 * 256) return;
  bfsplit(W5[i], Wh[i], Wl[i]);
}

__device__ inline void topk_insert(float d, int m, float* tv, int* ti) {
  if (d > tv[KNN - 1]) {      // strict >: ties keep earlier index (matches lax.top_k set)
    tv[KNN - 1] = d; ti[KNN - 1] = m;
    #pragma unroll
    for (int j = KNN - 1; j >= 1; --j) {
      if (tv[j] > tv[j - 1]) {
        float tf = tv[j - 1]; tv[j - 1] = tv[j]; tv[j] = tf;
        int tq = ti[j - 1]; ti[j - 1] = ti[j]; ti[j] = tq;
      } else break;
    }
  }
}

// kNN for C=3: cheap VALU version
__global__ __launch_bounds__(256) void k_knn3(const float* __restrict__ x, int ldb,
                                              int* __restrict__ idxout) {
  __shared__ __align__(16) float xl[NPT * 4];
  __shared__ float xx[NPT];
  int b = blockIdx.x;
  const float* xb = x + (size_t)b * ldb;
  for (int i = threadIdx.x; i < NPT; i += 256) {
    f4 v; v.x = xb[i]; v.y = xb[NPT + i]; v.z = xb[2 * NPT + i]; v.w = 0.f;
    *(f4*)&xl[i * 4] = v;
    xx[i] = v.x * v.x + v.y * v.y + v.z * v.z;
  }
  __syncthreads();
  int n = threadIdx.x;
  if (n >= NPT) return;
  f4 xn = *(const f4*)&xl[n * 4];
  float xxn = xx[n];
  float tv[KNN]; int ti[KNN];
  #pragma unroll
  for (int k = 0; k < KNN; ++k) { tv[k] = -1e30f; ti[k] = 0; }
  for (int m = 0; m < NPT; ++m) {
    f4 v = *(const f4*)&xl[m * 4];
    float dot = xn.x * v.x + xn.y * v.y + xn.z * v.z;
    topk_insert(2.f * dot - xxn - xx[m], m, tv, ti);
  }
  int* ib = idxout + ((size_t)b * NPT + n) * KNN;
  #pragma unroll
  for (int k = 0; k < KNN; ++k) ib[k] = ti[k];
}

// kNN via MFMA Gram matrix, 3-way bf16 split (6 products ~ fp32-exact).
template<int C>
__global__ __launch_bounds__(512) void k_knn_mfma(const float* __restrict__ x, int ldb,
                                                  int* __restrict__ idxout) {
  constexpr int KPG = C + 8;
  constexpr int SW = (C / 16) - 1;
  __shared__ __align__(16) unsigned short XH[224 * KPG];
  __shared__ __align__(16) unsigned short XM[224 * KPG];
  __shared__ __align__(16) unsigned short XL[224 * KPG];
  __shared__ float xx[224];
  int b = blockIdx.x;
  const float* xb = x + (size_t)b * ldb;
  for (int i = threadIdx.x; i < C * 224; i += 512) {
    int c = i / 224, m = i - c * 224;
    float v = (m < NPT) ? xb[c * NPT + m] : 0.f;
    unsigned short h = bfh(v);
    float r1 = v - bff(h);
    unsigned short mm = bfh(r1);
    unsigned short l = bfh(r1 - bff(mm));
    int cs = c ^ ((m & SW) << 4);
    XH[m * KPG + cs] = h; XM[m * KPG + cs] = mm; XL[m * KPG + cs] = l;
  }
  for (int m = threadIdx.x; m < 224; m += 512) {
    float s = 0.f;
    if (m < NPT) {
      for (int c = 0; c < C; ++c) { float v = xb[c * NPT + m]; s += v * v; }
    } else s = 1e30f;
    xx[m] = s;
  }
  __syncthreads();
  int w = threadIdx.x >> 6;
  int lane = threadIdx.x & 63;
  int lc = lane & 31, hi = lane >> 5;
  float tv[KNN]; int ti[KNN];
  #pragma unroll
  for (int k = 0; k < KNN; ++k) { tv[k] = -1e30f; ti[k] = 0; }
  if (w < 7) {
    int n = w * 32 + lc;
    f16v acc[7];
    #pragma unroll
    for (int mt = 0; mt < 7; ++mt)
      #pragma unroll
      for (int i = 0; i < 16; ++i) acc[mt][i] = 0.f;
    #pragma unroll
    for (int ks = 0; ks < C / 16; ++ks) {
      int kb = ks * 16 + hi * 8;
      int nsw = kb ^ ((n & SW) << 4);
      bf8v bh = *(const bf8v*)&XH[n * KPG + nsw];
      bf8v bm = *(const bf8v*)&XM[n * KPG + nsw];
      bf8v bl = *(const bf8v*)&XL[n * KPG + nsw];
      #pragma unroll
      for (int mt = 0; mt < 7; ++mt) {
        int mr = mt * 32 + lc;
        int msw = kb ^ ((mr & SW) << 4);
        bf8v ah = *(const bf8v*)&XH[mr * KPG + msw];
        bf8v am = *(const bf8v*)&XM[mr * KPG + msw];
        bf8v al = *(const bf8v*)&XL[mr * KPG + msw];
        acc[mt] = __builtin_amdgcn_mfma_f32_32x32x16_bf16(ah, bh, acc[mt], 0, 0, 0);
        acc[mt] = __builtin_amdgcn_mfma_f32_32x32x16_bf16(am, bh, acc[mt], 0, 0, 0);
        acc[mt] = __builtin_amdgcn_mfma_f32_32x32x16_bf16(ah, bm, acc[mt], 0, 0, 0);
        acc[mt] = __builtin_amdgcn_mfma_f32_32x32x16_bf16(am, bm, acc[mt], 0, 0, 0);
        acc[mt] = __builtin_amdgcn_mfma_f32_32x32x16_bf16(al, bh, acc[mt], 0, 0, 0);
        acc[mt] = __builtin_amdgcn_mfma_f32_32x32x16_bf16(ah, bl, acc[mt], 0, 0, 0);
      }
    }
    float xxn = xx[n];
    #pragma unroll
    for (int mt = 0; mt < 7; ++mt)
      #pragma unroll
      for (int i = 0; i < 16; ++i) {
        int m = mt * 32 + (i & 3) + 8 * (i >> 2) + 4 * hi;
        float d = 2.f * acc[mt][i] - xx[m] - xxn;
        topk_insert(d, m, tv, ti);
      }
  }
  __syncthreads();
  float* LV = (float*)XH;
  int* LI = (int*)XM;
  if (w < 7) {
    int slot = (w * 64 + lane) * KNN;
    #pragma unroll
    for (int k = 0; k < KNN; ++k) { LV[slot + k] = tv[k]; LI[slot + k] = ti[k]; }
  }
  __syncthreads();
  if (w < 7 && hi == 0) {
    int n = w * 32 + lc;
    if (n < NPT) {
      int sa = (w * 64 + lane) * KNN, sb = sa + 32 * KNN;
      int a = 0, bq = 0;
      int* ob = idxout + ((size_t)b * NPT + n) * KNN;
      #pragma unroll
      for (int k = 0; k < KNN; ++k) {
        float va = LV[sa + a], vb = LV[sb + bq];
        int ia = LI[sa + a], ic = LI[sb + bq];
        bool ta = (va > vb) || (va == vb && ia < ic);
        ob[k] = ta ? ia : ic;
        if (ta) ++a; else ++bq;
      }
    }
  }
}

// Fused edge conv — R12: 512 threads (16 waves/CU at 2 blocks/CU, 2x TLP).
// Per-output-element c-order identical to 256-thr version -> bitwise-same.
template<int CIN, int OG, bool WBF16, bool WF32>
__global__ __launch_bounds__(512, 4) void k_conv_fused(const float* __restrict__ x, int ldb,
    const float* __restrict__ W, const int* __restrict__ idxb, float* __restrict__ xout, int ldo,
    unsigned short* __restrict__ xch, unsigned short* __restrict__ xcl, int cbase) {
  constexpr int NPAD = 224;
  constexpr int DBS = 224;
  constexpr int REGION = 64 * DBS;
  __shared__ __align__(16) float smem[REGION + CIN * 64];
  __shared__ unsigned short idxl[NPT * KNN];
  float* xl = smem;
  float* db = smem;
  float* wl = smem + REGION;
  int d = blockIdx.x;
  int b, og;
  if (OG == 4)      { b = (d & 7) * 95 + (d >> 5); og = (d >> 3) & 3; }
  else if (OG == 2) { b = (d & 7) * 95 + (d >> 4); og = (d >> 3) & 1; }
  else              { b = d; og = 0; }
  if (b >= NB) return;
  const float* xb = x + (size_t)b * ldb;
  for (int i = threadIdx.x; i < CIN * NPAD; i += 512) {
    int c = i / NPAD, n = i - c * NPAD;
    xl[i] = (n < NPT) ? xb[c * NPT + n] : 0.f;
  }
  for (int i = threadIdx.x; i < 64 * CIN; i += 512) {
    int rl = i & 63, c = i >> 6;
    int o = og * 32 + (rl & 31);
    float wv = (rl < 32) ? W[o * 2 * CIN + c]
                         : (W[o * 2 * CIN + CIN + c] - W[o * 2 * CIN + c]);
    wl[c * 64 + rl] = wv;
  }
  for (int i = threadIdx.x; i < NPT * KNN; i += 512)
    idxl[i] = (unsigned short)idxb[(size_t)b * NPT * KNN + i];
  __syncthreads();
  int rq = threadIdx.x & 15, nq = threadIdx.x >> 4;   // nq in [0,32)
  int gv[2]; bool gok[2];
  #pragma unroll
  for (int j = 0; j < 2; ++j) { int g = nq + j * 32; gok[j] = g < 55; gv[j] = (g < 55 ? g : 54) * 4; }
  f4 acc[2][4];
  #pragma unroll
  for (int j = 0; j < 2; ++j)
    #pragma unroll
    for (int i2 = 0; i2 < 4; ++i2) acc[j][i2] = (f4){0.f, 0.f, 0.f, 0.f};
  #pragma unroll 2
  for (int c = 0; c < CIN; ++c) {
    f4 wv = *(const f4*)&wl[c * 64 + rq * 4];
    #pragma unroll
    for (int j = 0; j < 2; ++j) {
      f4 xv = *(const f4*)&xl[c * NPAD + gv[j]];
      acc[j][0] += wv.x * xv; acc[j][1] += wv.y * xv;
      acc[j][2] += wv.z * xv; acc[j][3] += wv.w * xv;
    }
  }
  __syncthreads();
  #pragma unroll
  for (int j = 0; j < 2; ++j) {
    if (gok[j]) {
      #pragma unroll
      for (int i2 = 0; i2 < 4; ++i2)
        *(f4*)&db[(rq * 4 + i2) * DBS + gv[j]] = acc[j][i2];
    }
  }
  __syncthreads();
  int o0 = og * 32;
  for (int i = threadIdx.x; i < 32 * 224; i += 512) {
    int ol = i / 224, n = i - ol * 224;
    unsigned short h = 0, l = 0;
    if (n < NPT) {
      const float* drow = &db[ol * DBS];
      const unsigned short* ib = &idxl[n * KNN];
      float mx = -1e30f;
      #pragma unroll
      for (int k = 0; k < KNN; ++k) mx = fmaxf(mx, drow[ib[k]]);
      float v = mx + db[(32 + ol) * DBS + n];
      v = (v >= 0.f) ? v : 0.2f * v;
      if (WF32) xout[((size_t)b * ldo + o0 + ol) * NPT + n] = v;
      if (WBF16) bfsplit(v, h, l);
    }
    if (WBF16) {
      int c = cbase + o0 + ol;
      size_t off = (((size_t)b * 32 + (c >> 3)) * 224 + n) * 8 + (c & 7);
      xch[off] = h;
      xcl[off] = l;
    }
  }
}

// W5 GEMM, pre-split path: B staging is a CONTIGUOUS bf16 memcpy.
__global__ __launch_bounds__(256) void k_w5_mfma_ps(
    const unsigned short* __restrict__ xch, const unsigned short* __restrict__ xcl,
    const unsigned short* __restrict__ Wh, const unsigned short* __restrict__ Wl,
    const float* __restrict__ g5, const float* __restrict__ b5, const float* __restrict__ m5,
    const float* __restrict__ v5, float* __restrict__ p) {
  __shared__ __align__(16) unsigned short XH[4 * 224 * 8];   // 14KB
  __shared__ __align__(16) unsigned short XL[4 * 224 * 8];
  int d = blockIdx.x;
  int b = (d & 7) * 95 + (d >> 5);
  int rg = (d >> 3) & 3;
  if (b >= NB) return;
  int lane = threadIdx.x & 63, w = threadIdx.x >> 6;
  f16v acc[7];
  #pragma unroll
  for (int t = 0; t < 7; ++t)
    #pragma unroll
    for (int i = 0; i < 16; ++i) acc[t][i] = 0.f;

  int r = rg * 128 + w * 32 + (lane & 31);
  int khalf = (lane >> 5) * 8;
  const u4v* srcH = (const u4v*)(xch + (size_t)b * 57344);   // 32*224*8
  const u4v* srcL = (const u4v*)(xcl + (size_t)b * 57344);
  u4v* dH = (u4v*)XH;
  u4v* dL = (u4v*)XL;

  for (int cb = 0; cb < 8; ++cb) {
    if (cb) __syncthreads();
    const u4v* sH = srcH + cb * 896;
    const u4v* sL = srcL + cb * 896;
    for (int i = threadIdx.x; i < 896; i += 256) {
      dH[i] = sH[i];
      dL[i] = sL[i];
    }
    __syncthreads();
    #pragma unroll
    for (int ks = 0; ks < 2; ++ks) {
      int kg = cb * 32 + ks * 16 + khalf;
      int g = ks * 2 + (lane >> 5);
      bf8v ah = *(const bf8v*)&Wh[(size_t)r * 256 + kg];
      bf8v al = *(const bf8v*)&Wl[(size_t)r * 256 + kg];
      #pragma unroll
      for (int t = 0; t < 7; ++t) {
        int col = t * 32 + (lane & 31);
        bf8v bh = *(const bf8v*)&XH[g * 1792 + col * 8];
        bf8v bl = *(const bf8v*)&XL[g * 1792 + col * 8];
        acc[t] = __builtin_amdgcn_mfma_f32_32x32x16_bf16(ah, bh, acc[t], 0, 0, 0);
        acc[t] = __builtin_amdgcn_mfma_f32_32x32x16_bf16(al, bh, acc[t], 0, 0, 0);
        acc[t] = __builtin_amdgcn_mfma_f32_32x32x16_bf16(ah, bl, acc[t], 0, 0, 0);
      }
    }
  }
  int rbase = rg * 128 + w * 32 + 4 * (lane >> 5);
  int lc = lane & 31;
  #pragma unroll
  for (int i = 0; i < 16; ++i) {
    int row = rbase + (i & 3) + 8 * (i >> 2);
    float a = g5[row] * rsqrtf(v5[row] + 1e-5f);
    float dq = b5[row] - m5[row] * a;
    float mx = -1e30f, sm = 0.f;
    #pragma unroll
    for (int t = 0; t < 7; ++t) {
      bool valid = (t < 6) || (lc < 28);
      float hv = a * acc[t][i] + dq;
      float lv = (hv >= 0.f) ? hv : 0.2f * hv;
      if (valid) { mx = fmaxf(mx, lv); sm += lv; }
    }
    #pragma unroll
    for (int m_ = 1; m_ <= 16; m_ <<= 1) {
      mx = fmaxf(mx, __shfl_xor(mx, m_));
      sm += __shfl_xor(sm, m_);
    }
    if (lc == 0) {
      p[(size_t)b * 1024 + row] = mx;
      p[(size_t)b * 1024 + 512 + row] = sm * (1.f / NPT);
    }
  }
}

// W5 GEMM fallback (exact R6 form, 280us known): inline split staging, KP=72.
#define KP 72
__global__ __launch_bounds__(256) void k_w5_mfma(const float* __restrict__ xc,
    const unsigned short* __restrict__ Wh, const unsigned short* __restrict__ Wl,
    const float* __restrict__ g5, const float* __restrict__ b5, const float* __restrict__ m5,
    const float* __restrict__ v5, float* __restrict__ p) {
  __shared__ __align__(16) unsigned short XH[224 * KP];
  __shared__ __align__(16) unsigned short XL[224 * KP];
  int d = blockIdx.x;
  int b = (d & 7) * 95 + (d >> 5);
  int rg = (d >> 3) & 3;
  if (b >= NB) return;
  int lane = threadIdx.x & 63, w = threadIdx.x >> 6;
  f16v acc[7];
  #pragma unroll
  for (int t = 0; t < 7; ++t)
    #pragma unroll
    for (int i = 0; i < 16; ++i) acc[t][i] = 0.f;

  int r = rg * 128 + w * 32 + (lane & 31);
  int khalf = (lane >> 5) * 8;

  for (int cb = 0; cb < 4; ++cb) {
    if (cb) __syncthreads();
    for (int i = threadIdx.x; i < 32 * NPT; i += 256) {
      int cp = i / NPT;
      int n = i - cp * NPT;
      int c0 = cp * 2;
      const float* src = &xc[((size_t)b * XCCH + cb * 64 + c0) * NPT + n];
      float x0 = src[0];
      float x1 = src[NPT];
      unsigned short h0, l0, h1, l1;
      bfsplit(x0, h0, l0); bfsplit(x1, h1, l1);
      ((unsigned*)XH)[(n * KP + c0) >> 1] = (unsigned)h0 | ((unsigned)h1 << 16);
      ((unsigned*)XL)[(n * KP + c0) >> 1] = (unsigned)l0 | ((unsigned)l1 << 16);
    }
    for (int i = threadIdx.x; i < 4 * 32; i += 256) {
      int n = NPT + (i >> 5); int cd = i & 31;
      ((unsigned*)XH)[n * (KP / 2) + cd] = 0u;
      ((unsigned*)XL)[n * (KP / 2) + cd] = 0u;
    }
    __syncthreads();
    #pragma unroll
    for (int ks = 0; ks < 4; ++ks) {
      int kg = cb * 64 + ks * 16 + khalf;
      int kl = ks * 16 + khalf;
      bf8v ah = *(const bf8v*)&Wh[(size_t)r * 256 + kg];
      bf8v al = *(const bf8v*)&Wl[(size_t)r * 256 + kg];
      #pragma unroll
      for (int t = 0; t < 7; ++t) {
        int col = t * 32 + (lane & 31);
        bf8v bh = *(const bf8v*)&XH[col * KP + kl];
        bf8v bl = *(const bf8v*)&XL[col * KP + kl];
        acc[t] = __builtin_amdgcn_mfma_f32_32x32x16_bf16(ah, bh, acc[t], 0, 0, 0);
        acc[t] = __builtin_amdgcn_mfma_f32_32x32x16_bf16(al, bh, acc[t], 0, 0, 0);
        acc[t] = __builtin_amdgcn_mfma_f32_32x32x16_bf16(ah, bl, acc[t], 0, 0, 0);
      }
    }
  }
  int rbase = rg * 128 + w * 32 + 4 * (lane >> 5);
  int lc = lane & 31;
  #pragma unroll
  for (int i = 0; i < 16; ++i) {
    int row = rbase + (i & 3) + 8 * (i >> 2);
    float a = g5[row] * rsqrtf(v5[row] + 1e-5f);
    float dq = b5[row] - m5[row] * a;
    float mx = -1e30f, sm = 0.f;
    #pragma unroll
    for (int t = 0; t < 7; ++t) {
      bool valid = (t < 6) || (lc < 28);
      float hv = a * acc[t][i] + dq;
      float lv = (hv >= 0.f) ? hv : 0.2f * hv;
      if (valid) { mx = fmaxf(mx, lv); sm += lv; }
    }
    #pragma unroll
    for (int m_ = 1; m_ <= 16; m_ <<= 1) {
      mx = fmaxf(mx, __shfl_xor(mx, m_));
      sm += __shfl_xor(sm, m_);
    }
    if (lc == 0) {
      p[(size_t)b * 1024 + row] = mx;
      p[(size_t)b * 1024 + 512 + row] = sm * (1.f / NPT);
    }
  }
}

// out[b][o] = in[b][:] . Wt[o][:]  (+ bn+leaky | + bias)
template<int ON, bool FUSE>
__global__ __launch_bounds__(256) void k_fc(const float* __restrict__ in, const float* __restrict__ Wt,
    const float* __restrict__ q0, const float* __restrict__ q1, const float* __restrict__ q2,
    const float* __restrict__ q3, float* __restrict__ out, int ostride) {
  __shared__ __align__(16) float il[32 * 68];
  __shared__ __align__(16) float wl[32 * 68];
  int b0 = blockIdx.x * 64, o0 = blockIdx.y * 64;
  int oq = threadIdx.x & 15, bq = threadIdx.x >> 4;
  f4 acc[4];
  #pragma unroll
  for (int i2 = 0; i2 < 4; ++i2) acc[i2] = (f4){0.f, 0.f, 0.f, 0.f};
  for (int cb = 0; cb < 32; ++cb) {
    if (cb) __syncthreads();
    for (int i = threadIdx.x; i < 2048; i += 256) {
      int c = i & 31, bb = i >> 5;
      il[c * 68 + bb] = (b0 + bb < NB) ? in[(b0 + bb) * 1024 + cb * 32 + c] : 0.f;
    }
    for (int i = threadIdx.x; i < 2048; i += 256) {
      int c = i & 31, ol = i >> 5;
      wl[c * 68 + ol] = (o0 + ol < ON) ? Wt[(o0 + ol) * 1024 + cb * 32 + c] : 0.f;
    }
    __syncthreads();
    #pragma unroll
    for (int c = 0; c < 32; ++c) {
      f4 wv = *(const f4*)&wl[c * 68 + oq * 4];
      f4 iv = *(const f4*)&il[c * 68 + bq * 4];
      acc[0] += wv.x * iv; acc[1] += wv.y * iv; acc[2] += wv.z * iv; acc[3] += wv.w * iv;
    }
  }
  #pragma unroll
  for (int i2 = 0; i2 < 4; ++i2) {
    int o = o0 + oq * 4 + i2;
    if (o >= ON) continue;
    float A = 1.f, Dv = 0.f;
    if (FUSE) { float a = q0[o] * rsqrtf(q3[o] + 1e-5f); A = a; Dv = q1[o] - q2[o] * a; }
    else { Dv = q0[o]; }
    #pragma unroll
    for (int jj = 0; jj < 4; ++jj) {
      int bb = b0 + bq * 4 + jj;
      if (bb < NB) {
        float v = acc[i2][jj];
        if (FUSE) { v = A * v + Dv; v = (v >= 0.f) ? v : 0.2f * v; }
        else { v = v + Dv; }
        out[(size_t)bb * ostride + o] = v;
      }
    }
  }
}

extern "C" void kernel_launch(void* const* d_in, const int* in_sizes, int n_in,
                              void* d_out, int out_size, void* d_ws, size_t ws_size,
                              hipStream_t stream) {
  const float* input = (const float*)d_in[0];
  const float* W1 = (const float*)d_in[1];
  const float* W2 = (const float*)d_in[2];
  const float* W3 = (const float*)d_in[3];
  const float* W4 = (const float*)d_in[4];
  const float* W5 = (const float*)d_in[5];
  const float* g5 = (const float*)d_in[6];
  const float* b5 = (const float*)d_in[7];
  const float* m5 = (const float*)d_in[8];
  const float* v5 = (const float*)d_in[9];
  const float* Wl1 = (const float*)d_in[10];
  const float* g6 = (const float*)d_in[11];
  const float* b6 = (const float*)d_in[12];
  const float* m6 = (const float*)d_in[13];
  const float* v6 = (const float*)d_in[14];
  const float* Wl2 = (const float*)d_in[15];
  const float* bl2 = (const float*)d_in[16];

  float* w = (float*)d_ws;
  // ps layout (275.0 MB): xc holds only 128 fp32 channels (x1..x3); x4 exists
  // only as bf16 h/l. Fallback layout (186.4 MB): 256-ch fp32 xc, no h/l.
  bool ps = ws_size >= 276000000ull;

  float *x0, *xc, *p, *z; int* idxb;
  unsigned short *wh, *wlo, *xch, *xcl;
  int ldxc, ldo;
  if (ps) {
    x0 = w;                               //      500,940
    xc = x0 + 500940;                     //   21,373,440 (759*128*220)
    p  = xc + 21373440;                   //      777,216
    z  = p  + 777216;                     //      777,216
    idxb = (int*)(z + 777216);            //    1,669,800 ints
    wh  = (unsigned short*)(w + 25098612);
    wlo = wh + 131072;
    xch = wlo + 131072;                   //   43,524,096 shorts
    xcl = xch + 43524096;                 //   43,524,096 shorts
    ldxc = 128 * NPT; ldo = 128;
  } else {
    x0 = w;
    xc = x0 + 500940;                     //   42,746,880 (759*256*220)
    p  = xc + 42746880;
    z  = p  + 777216;
    idxb = (int*)(z + 777216);
    wh  = (unsigned short*)(w + 46472052);
    wlo = wh + 131072;
    xch = wlo; xcl = wlo;                 // unused (WBF16=false)
    ldxc = LDXC; ldo = XCCH;
  }

  k_transpose<<<1957, 256, 0, stream>>>(input, x0);
  k_w5split<<<512, 256, 0, stream>>>(W5, wh, wlo);

  k_knn3<<<759, 256, 0, stream>>>(x0, 3 * NPT, idxb);

  if (ps) {
    k_conv_fused<3, 1, true, true><<<759, 512, 0, stream>>>(x0, 3 * NPT, W1, idxb, xc, ldo, xch, xcl, 0);
    k_knn_mfma<32><<<759, 512, 0, stream>>>(xc, ldxc, idxb);
    k_conv_fused<32, 1, true, true><<<759, 512, 0, stream>>>(xc, ldxc, W2, idxb, xc + 32 * NPT, ldo, xch, xcl, 32);
    k_knn_mfma<32><<<759, 512, 0, stream>>>(xc + 32 * NPT, ldxc, idxb);
    k_conv_fused<32, 2, true, true><<<1520, 512, 0, stream>>>(xc + 32 * NPT, ldxc, W3, idxb, xc + 64 * NPT, ldo, xch, xcl, 64);
    k_knn_mfma<64><<<759, 512, 0, stream>>>(xc + 64 * NPT, ldxc, idxb);
    k_conv_fused<64, 4, true, false><<<3040, 512, 0, stream>>>(xc + 64 * NPT, ldxc, W4, idxb, xc, 0, xch, xcl, 128);
    k_w5_mfma_ps<<<3040, 256, 0, stream>>>(xch, xcl, wh, wlo, g5, b5, m5, v5, p);
  } else {
    k_conv_fused<3, 1, false, true><<<759, 512, 0, stream>>>(x0, 3 * NPT, W1, idxb, xc, ldo, xch, xcl, 0);
    k_knn_mfma<32><<<759, 512, 0, stream>>>(xc, ldxc, idxb);
    k_conv_fused<32, 1, false, true><<<759, 512, 0, stream>>>(xc, ldxc, W2, idxb, xc + 32 * NPT, ldo, xch, xcl, 32);
    k_knn_mfma<32><<<759, 512, 0, stream>>>(xc + 32 * NPT, ldxc, idxb);
    k_conv_fused<32, 2, false, true><<<1520, 512, 0, stream>>>(xc + 32 * NPT, ldxc, W3, idxb, xc + 64 * NPT, ldo, xch, xcl, 64);
    k_knn_mfma<64><<<759, 512, 0, stream>>>(xc + 64 * NPT, ldxc, idxb);
    k_conv_fused<64, 4, false, true><<<3040, 512, 0, stream>>>(xc + 64 * NPT, ldxc, W4, idxb, xc + 128 * NPT, ldo, xch, xcl, 128);
    k_w5_mfma<<<3040, 256, 0, stream>>>(xc, wh, wlo, g5, b5, m5, v5, p);
  }

  k_fc<1024, true><<<dim3(12, 16), 256, 0, stream>>>(p, Wl1, g6, b6, m6, v6, z, 1024);
  k_fc<380, false><<<dim3(12, 6), 256, 0, stream>>>(z, Wl2, bl2, bl2, bl2, bl2, (float*)d_out, 380);
}